// Round 1
// baseline (2259.207 us; speedup 1.0000x reference)
//
#include <hip/hip_runtime.h>
#include <stdint.h>

#define Bz   4
#define Sq   2048
#define Dm   1024
#define Hh   16
#define HDm  64
#define DFFm 4096
#define Vv   32000
#define MTOK (Bz * Sq)   // 8192

typedef unsigned short u16;
typedef __attribute__((ext_vector_type(8))) short short8v;   // 8 bf16 = 4 VGPR (MFMA frag)
typedef __attribute__((ext_vector_type(4))) float f32x4;

struct alignas(8) U16x4 { u16 x, y, z, w; };

typedef const __attribute__((address_space(1))) void* gptr1_t;
typedef __attribute__((address_space(3))) void* lptr3_t;

__device__ __forceinline__ u16 f2bf(float f) {
    union { float f; unsigned u; } v; v.f = f;
    unsigned r = v.u + 0x7FFF + ((v.u >> 16) & 1);   // RNE
    return (u16)(r >> 16);
}
__device__ __forceinline__ float bf2f(u16 h) {
    union { unsigned u; float f; } v; v.u = ((unsigned)h) << 16;
    return v.f;
}

// ---------------------------------------------------------------------------
// fp32 -> bf16 conversion (vectorized, grid-stride)
// ---------------------------------------------------------------------------
__global__ void to_bf16(const float* __restrict__ in, u16* __restrict__ out, long n4) {
    long i = (long)blockIdx.x * blockDim.x + threadIdx.x;
    const long stride = (long)gridDim.x * blockDim.x;
    for (; i < n4; i += stride) {
        float4 v = *(const float4*)(in + i * 4);
        U16x4 h = { f2bf(v.x), f2bf(v.y), f2bf(v.z), f2bf(v.w) };
        *(U16x4*)(out + i * 4) = h;
    }
}

// ---------------------------------------------------------------------------
// embedding + positional: x = emb[tok] + pos ; writes fp32 and bf16 copies
// ---------------------------------------------------------------------------
__global__ void embed_kernel(const int* __restrict__ tok, const float* __restrict__ emb,
                             const float* __restrict__ pos, float* __restrict__ x32,
                             u16* __restrict__ x16) {
    const int row = blockIdx.x;            // b*S + s
    const int s = row & (Sq - 1);
    const int t = threadIdx.x;             // 256 threads * 4 floats = 1024
    const long tokid = tok[row];
    float4 e = *(const float4*)(emb + tokid * Dm + t * 4);
    float4 p = *(const float4*)(pos + (long)s * Dm + t * 4);
    float4 v = { e.x + p.x, e.y + p.y, e.z + p.z, e.w + p.w };
    const long base = (long)row * Dm + t * 4;
    *(float4*)(x32 + base) = v;
    U16x4 h = { f2bf(v.x), f2bf(v.y), f2bf(v.z), f2bf(v.w) };
    *(U16x4*)(x16 + base) = h;
}

// ---------------------------------------------------------------------------
// GEMM (m97 structure): C[M,N] = alpha * A[M,K] * B[N,K]^T + bias
// 128x128 tile, BK=32, 4 waves (2x2), mfma_f32_16x16x32_bf16,
// global_load_lds width=16 staging. Batched via blockIdx.z with 2-level strides.
// OUTMODE: 0 = fp32 out, 1 = bf16 out.  RELU applied after bias.
// ---------------------------------------------------------------------------
template <int OUTMODE, int RELU>
__global__ __launch_bounds__(256) void gemm_bt(
    const u16* __restrict__ A, const u16* __restrict__ B,
    const float* __restrict__ bias, void* __restrict__ Cp,
    int M, int N, int K, int lda, int ldb, int ldc,
    int zi, long sAo, long sAi, long sBo, long sBi, long sCo, long sCi,
    float alpha)
{
    __shared__ u16 As[128 * 32];
    __shared__ u16 Bs[128 * 32];

    const int bz = blockIdx.z;
    A += (long)(bz / zi) * sAo + (long)(bz % zi) * sAi;
    B += (long)(bz / zi) * sBo + (long)(bz % zi) * sBi;
    const long offC = (long)(bz / zi) * sCo + (long)(bz % zi) * sCi;

    const int tm = blockIdx.x * 128;
    const int tn = blockIdx.y * 128;
    const int t = threadIdx.x;
    const int wave = t >> 6;
    const int lane = t & 63;
    const int wr = (wave >> 1) * 64;   // wave row base in tile
    const int wc = (wave & 1) * 64;    // wave col base in tile

    f32x4 acc[4][4];
#pragma unroll
    for (int m = 0; m < 4; ++m)
#pragma unroll
        for (int n = 0; n < 4; ++n) acc[m][n] = f32x4{0.f, 0.f, 0.f, 0.f};

    const int srow = t >> 2;            // staging: row = t/4 (+64*i)
    const int scol = (t & 3) * 8;       // staging: 8 bf16 (16B) per thread
    const int fr = lane & 15;
    const int kg = (lane >> 4) * 8;

    for (int k0 = 0; k0 < K; k0 += 32) {
        __syncthreads();
#pragma unroll
        for (int i = 0; i < 2; ++i) {
            int gr = tm + srow + i * 64; if (gr > M - 1) gr = M - 1;
            const u16* gp = A + (long)gr * lda + (k0 + scol);
            __builtin_amdgcn_global_load_lds((gptr1_t)gp, (lptr3_t)(As + i * 2048 + t * 8), 16, 0, 0);
        }
#pragma unroll
        for (int i = 0; i < 2; ++i) {
            int gr = tn + srow + i * 64; if (gr > N - 1) gr = N - 1;
            const u16* gp = B + (long)gr * ldb + (k0 + scol);
            __builtin_amdgcn_global_load_lds((gptr1_t)gp, (lptr3_t)(Bs + i * 2048 + t * 8), 16, 0, 0);
        }
        __syncthreads();   // compiler drains vmcnt(0) here

        short8v af[4], bf[4];
#pragma unroll
        for (int m = 0; m < 4; ++m)
            af[m] = *(const short8v*)(As + (wr + m * 16 + fr) * 32 + kg);
#pragma unroll
        for (int n = 0; n < 4; ++n)
            bf[n] = *(const short8v*)(Bs + (wc + n * 16 + fr) * 32 + kg);
#pragma unroll
        for (int m = 0; m < 4; ++m)
#pragma unroll
            for (int n = 0; n < 4; ++n)
                acc[m][n] = __builtin_amdgcn_mfma_f32_16x16x32_bf16(af[m], bf[n], acc[m][n], 0, 0, 0);
    }

    // epilogue: C/D layout col = lane&15, row = (lane>>4)*4 + reg  [m89]
    const int rq = (lane >> 4) * 4;
#pragma unroll
    for (int m = 0; m < 4; ++m) {
#pragma unroll
        for (int n = 0; n < 4; ++n) {
            const int col = tn + wc + n * 16 + fr;
            if (col >= N) continue;
            const float bv = bias ? bias[col] : 0.f;
#pragma unroll
            for (int r = 0; r < 4; ++r) {
                const int row = tm + wr + m * 16 + rq + r;
                if (row >= M) continue;
                float v = alpha * acc[m][n][r] + bv;
                if (RELU) v = v > 0.f ? v : 0.f;
                if (OUTMODE == 0)
                    ((float*)Cp)[offC + (long)row * ldc + col] = v;
                else
                    ((u16*)Cp)[offC + (long)row * ldc + col] = f2bf(v);
            }
        }
    }
}

// ---------------------------------------------------------------------------
// V transpose: vt[bh, d, k] = qkv[b, k, 2D + h*64 + d]  (bf16)
// grid (Sq/64, B*H), block 256. LDS 64x72 (16B-aligned rows, spread banks).
// ---------------------------------------------------------------------------
__global__ void transpose_v(const u16* __restrict__ qkv, u16* __restrict__ vt) {
    const int kt = blockIdx.x * 64;
    const int bh = blockIdx.y;
    const int b = bh >> 4, h = bh & 15;
    const int t = threadIdx.x;
    __shared__ u16 tile[64][72];
    const long src = (long)b * Sq * (3 * Dm) + 2 * Dm + h * HDm;
#pragma unroll
    for (int i = 0; i < 2; ++i) {
        const int kl = i * 32 + (t >> 3);
        const int d0 = (t & 7) * 8;
        short8v v = *(const short8v*)(qkv + src + (long)(kt + kl) * (3 * Dm) + d0);
        *(short8v*)(&tile[kl][d0]) = v;
    }
    __syncthreads();
#pragma unroll
    for (int i = 0; i < 2; ++i) {
        const int d = i * 32 + (t >> 3);
        const int kk0 = (t & 7) * 8;
        short8v o;
#pragma unroll
        for (int j = 0; j < 8; ++j) o[j] = (short)tile[kk0 + j][d];
        *(short8v*)(vt + ((long)bh * HDm + d) * Sq + kt + kk0) = o;
    }
}

// ---------------------------------------------------------------------------
// row softmax over 2048 bf16, in place. grid = B*H*S rows, block 256.
// ---------------------------------------------------------------------------
__global__ void softmax_rows(u16* __restrict__ sc) {
    const long row = blockIdx.x;
    u16* p = sc + row * Sq;
    const int t = threadIdx.x;
    const int wave = t >> 6, lane = t & 63;
    __shared__ float rm[4], rsum[4];

    short8v v = *(const short8v*)(p + t * 8);
    float f[8];
#pragma unroll
    for (int j = 0; j < 8; ++j) f[j] = bf2f((u16)v[j]);
    float mx = f[0];
#pragma unroll
    for (int j = 1; j < 8; ++j) mx = fmaxf(mx, f[j]);
#pragma unroll
    for (int o = 32; o; o >>= 1) mx = fmaxf(mx, __shfl_xor(mx, o));
    if (lane == 0) rm[wave] = mx;
    __syncthreads();
    mx = fmaxf(fmaxf(rm[0], rm[1]), fmaxf(rm[2], rm[3]));

    float sum = 0.f;
#pragma unroll
    for (int j = 0; j < 8; ++j) { f[j] = __expf(f[j] - mx); sum += f[j]; }
#pragma unroll
    for (int o = 32; o; o >>= 1) sum += __shfl_xor(sum, o);
    if (lane == 0) rsum[wave] = sum;
    __syncthreads();
    sum = rsum[0] + rsum[1] + rsum[2] + rsum[3];
    const float inv = 1.f / sum;

    short8v o;
#pragma unroll
    for (int j = 0; j < 8; ++j) o[j] = (short)f2bf(f[j] * inv);
    *(short8v*)(p + t * 8) = o;
}

// ---------------------------------------------------------------------------
// residual + LayerNorm. Reads x (fp32) and res (fp32); writes bf16 out16,
// and (if W32) the normalized result back into x in place (needed as the
// residual input of the NEXT block).
// ---------------------------------------------------------------------------
template <int W32>
__global__ void ln_kernel(float* __restrict__ x, const float* __restrict__ res,
                          const float* __restrict__ g, const float* __restrict__ be,
                          u16* __restrict__ out16) {
    const int row = blockIdx.x;
    const int t = threadIdx.x;
    const long base = (long)row * Dm + t * 4;
    float4 a = *(const float4*)(x + base);
    float4 b = *(const float4*)(res + base);
    float v0 = a.x + b.x, v1 = a.y + b.y, v2 = a.z + b.z, v3 = a.w + b.w;
    float s = v0 + v1 + v2 + v3;
    float q = v0 * v0 + v1 * v1 + v2 * v2 + v3 * v3;

    const int wave = t >> 6, lane = t & 63;
    __shared__ float rs[4], rq2[4];
#pragma unroll
    for (int o = 32; o; o >>= 1) { s += __shfl_xor(s, o); q += __shfl_xor(q, o); }
    if (lane == 0) { rs[wave] = s; rq2[wave] = q; }
    __syncthreads();
    s = rs[0] + rs[1] + rs[2] + rs[3];
    q = rq2[0] + rq2[1] + rq2[2] + rq2[3];

    const float mean = s * (1.f / Dm);
    const float var = q * (1.f / Dm) - mean * mean;
    const float rstd = rsqrtf(var + 1e-5f);
    const float4 gg = *(const float4*)(g + t * 4);
    const float4 bb = *(const float4*)(be + t * 4);
    float o0 = (v0 - mean) * rstd * gg.x + bb.x;
    float o1 = (v1 - mean) * rstd * gg.y + bb.y;
    float o2 = (v2 - mean) * rstd * gg.z + bb.z;
    float o3 = (v3 - mean) * rstd * gg.w + bb.w;
    U16x4 h = { f2bf(o0), f2bf(o1), f2bf(o2), f2bf(o3) };
    *(U16x4*)(out16 + base) = h;
    if (W32) {
        float4 ov = { o0, o1, o2, o3 };
        *(float4*)(x + base) = ov;
    }
}

// ---------------------------------------------------------------------------
extern "C" void kernel_launch(void* const* d_in, const int* in_sizes, int n_in,
                              void* d_out, int out_size, void* d_ws, size_t ws_size,
                              hipStream_t stream) {
    const int*   tokens = (const int*)  d_in[0];
    const float* emb    = (const float*)d_in[1];
    const float* pos    = (const float*)d_in[2];
    const float* w_qkv  = (const float*)d_in[3];
    const float* b_qkv  = (const float*)d_in[4];
    const float* w_o    = (const float*)d_in[5];
    const float* b_o    = (const float*)d_in[6];
    const float* g1     = (const float*)d_in[7];
    const float* beta1  = (const float*)d_in[8];
    const float* w1     = (const float*)d_in[9];
    const float* b1     = (const float*)d_in[10];
    const float* w2     = (const float*)d_in[11];
    const float* b2     = (const float*)d_in[12];
    const float* g2     = (const float*)d_in[13];
    const float* beta2  = (const float*)d_in[14];
    const float* w_fc   = (const float*)d_in[15];
    const float* b_fc   = (const float*)d_in[16];

    char* ws = (char*)d_ws;
    size_t off = 0;
    auto alloc = [&](size_t bytes) { void* p = ws + off; off += (bytes + 255) & ~(size_t)255; return p; };

    float* X32   = (float*)alloc((size_t)MTOK * Dm * 4);          // x fp32 (then x1 in place)
    u16*   XB16  = (u16*)  alloc((size_t)MTOK * Dm * 2);          // x bf16 (then x1, x2 in place)
    u16*   QKV16 = (u16*)  alloc((size_t)MTOK * 3 * Dm * 2);      // qkv bf16
    u16*   VT16  = (u16*)  alloc((size_t)64 * HDm * Sq * 2);      // V^T per head, bf16
    u16*   CTX16 = (u16*)  alloc((size_t)MTOK * Dm * 2);          // attention context bf16
    float* ATT32 = (float*)alloc((size_t)MTOK * Dm * 4);          // attn_out fp32 (then ffn_out)
    u16*   H16   = (u16*)  alloc((size_t)MTOK * DFFm * 2);        // FFN hidden bf16
    u16*   WQ16  = (u16*)  alloc((size_t)3 * Dm * Dm * 2);
    u16*   WO16  = (u16*)  alloc((size_t)Dm * Dm * 2);
    u16*   W116  = (u16*)  alloc((size_t)DFFm * Dm * 2);
    u16*   W216  = (u16*)  alloc((size_t)Dm * DFFm * 2);
    u16*   WFC16 = (u16*)  alloc((size_t)Vv * Dm * 2);
    u16*   SC16  = (u16*)d_out;   // scores scratch: 64*2048*2048*2 = 537MB < 1GB d_out

    const dim3 blk(256);

    // --- weight conversions (recomputed every call; deterministic) ---
    to_bf16<<<1024, blk, 0, stream>>>(w_qkv, WQ16, (long)3 * Dm * Dm / 4);
    to_bf16<<<1024, blk, 0, stream>>>(w_o,   WO16, (long)Dm * Dm / 4);
    to_bf16<<<1024, blk, 0, stream>>>(w1,    W116, (long)DFFm * Dm / 4);
    to_bf16<<<1024, blk, 0, stream>>>(w2,    W216, (long)Dm * DFFm / 4);
    to_bf16<<<2048, blk, 0, stream>>>(w_fc,  WFC16, (long)Vv * Dm / 4);

    // --- embedding ---
    embed_kernel<<<MTOK, blk, 0, stream>>>(tokens, emb, pos, X32, XB16);

    // --- QKV projection: [8192,3072] bf16 ---
    gemm_bt<1, 0><<<dim3(MTOK / 128, (3 * Dm) / 128, 1), blk, 0, stream>>>(
        XB16, WQ16, b_qkv, QKV16, MTOK, 3 * Dm, Dm, Dm, Dm, 3 * Dm,
        1, 0, 0, 0, 0, 0, 0, 1.f);

    // --- V transpose for PV GEMM ---
    transpose_v<<<dim3(Sq / 64, Bz * Hh), blk, 0, stream>>>(QKV16, VT16);

    // --- scores = 0.125 * Q K^T per (b,h): M=N=2048, K=64, batch=64 ---
    gemm_bt<1, 0><<<dim3(Sq / 128, Sq / 128, Bz * Hh), blk, 0, stream>>>(
        QKV16, QKV16 + Dm, nullptr, SC16, Sq, Sq, HDm, 3 * Dm, 3 * Dm, Sq,
        Hh, (long)Sq * 3 * Dm, HDm, (long)Sq * 3 * Dm, HDm,
        (long)Hh * Sq * Sq, (long)Sq * Sq, 0.125f);

    // --- softmax in place ---
    softmax_rows<<<Bz * Hh * Sq, blk, 0, stream>>>(SC16);

    // --- ctx = P V per (b,h): M=2048, N=64, K=2048 ---
    gemm_bt<1, 0><<<dim3(Sq / 128, 1, Bz * Hh), blk, 0, stream>>>(
        SC16, VT16, nullptr, CTX16, Sq, HDm, Sq, Sq, Sq, Dm,
        Hh, (long)Hh * Sq * Sq, (long)Sq * Sq,
        (long)Hh * HDm * Sq, (long)HDm * Sq,
        (long)Sq * Dm, (long)HDm, 1.f);

    // --- attn_out = ctx @ w_o^T + b_o (fp32) ---
    gemm_bt<0, 0><<<dim3(MTOK / 128, Dm / 128, 1), blk, 0, stream>>>(
        CTX16, WO16, b_o, ATT32, MTOK, Dm, Dm, Dm, Dm, Dm,
        1, 0, 0, 0, 0, 0, 0, 1.f);

    // --- LN1: x1 = LN(x + attn_out) -> X32 (in place) + XB16 ---
    ln_kernel<1><<<MTOK, blk, 0, stream>>>(X32, ATT32, g1, beta1, XB16);

    // --- FFN1: h = relu(x1 @ w1^T + b1) bf16 ---
    gemm_bt<1, 1><<<dim3(MTOK / 128, DFFm / 128, 1), blk, 0, stream>>>(
        XB16, W116, b1, H16, MTOK, DFFm, Dm, Dm, Dm, DFFm,
        1, 0, 0, 0, 0, 0, 0, 1.f);

    // --- FFN2: ffn = h @ w2^T + b2 (fp32 into ATT32) ---
    gemm_bt<0, 0><<<dim3(MTOK / 128, Dm / 128, 1), blk, 0, stream>>>(
        H16, W216, b2, ATT32, MTOK, Dm, DFFm, DFFm, DFFm, Dm,
        1, 0, 0, 0, 0, 0, 0, 1.f);

    // --- LN2: x2 = LN(x1 + ffn) -> XB16 only ---
    ln_kernel<0><<<MTOK, blk, 0, stream>>>(X32, ATT32, g2, beta2, XB16);

    // --- final vocab projection: logits = x2 @ w_fc^T + b_fc (fp32 -> d_out) ---
    gemm_bt<0, 0><<<dim3(MTOK / 128, Vv / 128, 1), blk, 0, stream>>>(
        XB16, WFC16, b_fc, (float*)d_out, MTOK, Vv, Dm, Dm, Dm, Vv,
        1, 0, 0, 0, 0, 0, 0, 1.f);
}

// Round 2
// 1838.624 us; speedup vs baseline: 1.2287x; 1.2287x over previous
//
#include <hip/hip_runtime.h>
#include <stdint.h>

#define Bz   4
#define Sq   2048
#define Dm   1024
#define Hh   16
#define HDm  64
#define DFFm 4096
#define Vv   32000
#define MTOK (Bz * Sq)   // 8192

typedef unsigned short u16;
typedef __attribute__((ext_vector_type(8))) short short8v;   // 8 bf16 = 4 VGPR (MFMA frag)
typedef __attribute__((ext_vector_type(4))) float f32x4;

struct alignas(8) U16x4 { u16 x, y, z, w; };

typedef const __attribute__((address_space(1))) void* gptr1_t;
typedef __attribute__((address_space(3))) void* lptr3_t;

__device__ __forceinline__ u16 f2bf(float f) {
    union { float f; unsigned u; } v; v.f = f;
    unsigned r = v.u + 0x7FFF + ((v.u >> 16) & 1);   // RNE
    return (u16)(r >> 16);
}
__device__ __forceinline__ float bf2f(u16 h) {
    union { unsigned u; float f; } v; v.u = ((unsigned)h) << 16;
    return v.f;
}

#define WAITVM(N) asm volatile("s_waitcnt vmcnt(" #N ")" ::: "memory")

__device__ __forceinline__ void barrier_fenced() {
    asm volatile("" ::: "memory");          // no sink of ds_reads below barrier
    __builtin_amdgcn_s_barrier();
    asm volatile("" ::: "memory");          // no hoist of next phase's ops above
}

// ---------------------------------------------------------------------------
// fp32 -> bf16 conversion (vectorized, grid-stride)
// ---------------------------------------------------------------------------
__global__ void to_bf16(const float* __restrict__ in, u16* __restrict__ out, long n4) {
    long i = (long)blockIdx.x * blockDim.x + threadIdx.x;
    const long stride = (long)gridDim.x * blockDim.x;
    for (; i < n4; i += stride) {
        float4 v = *(const float4*)(in + i * 4);
        U16x4 h = { f2bf(v.x), f2bf(v.y), f2bf(v.z), f2bf(v.w) };
        *(U16x4*)(out + i * 4) = h;
    }
}

// ---------------------------------------------------------------------------
// embedding + positional: x = emb[tok] + pos ; writes fp32 and bf16 copies
// ---------------------------------------------------------------------------
__global__ void embed_kernel(const int* __restrict__ tok, const float* __restrict__ emb,
                             const float* __restrict__ pos, float* __restrict__ x32,
                             u16* __restrict__ x16) {
    const int row = blockIdx.x;            // b*S + s
    const int s = row & (Sq - 1);
    const int t = threadIdx.x;             // 256 threads * 4 floats = 1024
    const long tokid = tok[row];
    float4 e = *(const float4*)(emb + tokid * Dm + t * 4);
    float4 p = *(const float4*)(pos + (long)s * Dm + t * 4);
    float4 v = { e.x + p.x, e.y + p.y, e.z + p.z, e.w + p.w };
    const long base = (long)row * Dm + t * 4;
    *(float4*)(x32 + base) = v;
    U16x4 h = { f2bf(v.x), f2bf(v.y), f2bf(v.z), f2bf(v.w) };
    *(U16x4*)(x16 + base) = h;
}

// ===========================================================================
// 256x256 8-phase GEMM (T2+T3+T4+T5): C[M,N] = alpha*A[M,K]*B[N,K]^T + bias
// Requires: M%256==0, N%256==0, K%64==0, nt=K/64 >= 4, grid %8 == 0.
// 512 threads = 8 waves (2M x 4N), per-wave 128x64 output, BK=64.
// LDS 128 KiB: 2 bufs x (A 256x64 | B 256x64) bf16, XOR-swizzled (col8 ^= row&7)
// via pre-swizzled global_load_lds source + swizzled ds_read (rule #21).
// Schedule per K-tile (4 phases), staging 1 half-tile (2 gload_lds) per phase:
//   p0: read A m0-3 (kk0,1) + B n0-3 (kk0,1); stage B(t+1).h0->nxt; MFMA m0-3 kk0
//   p1: read A m4-7 (kk0,1);                  stage B(t+1).h1->nxt; MFMA m0-3 kk1
//   p2:                                       stage A(t+2).h0->cur; MFMA m4-7 kk0
//   p3:                                       stage A(t+2).h1->cur; vmcnt(4); MFMA m4-7 kk1
// Race-freedom: all reads of cur happen p0-p1; stage into cur only at p2-p3,
// separated by fenced barriers. vmcnt(4) at p3 guarantees tile t+1 complete
// (only the 2 A(t+2) halves, 4 loads, were issued after B(t+1).h1).
// ===========================================================================
template <int OUTMODE, int RELU>
__global__ __launch_bounds__(512, 2) void gemm256(
    const u16* __restrict__ A, const u16* __restrict__ B,
    const float* __restrict__ bias, void* __restrict__ Cp,
    int M, int N, int K, float alpha, int mtiles)
{
    __shared__ u16 smem[65536];   // 128 KiB

    // bijective XCD swizzle (grid % 8 == 0)
    const int nwg = gridDim.x;
    const int bid = blockIdx.x;
    const int cpx = nwg >> 3;
    const int swz = (bid & 7) * cpx + (bid >> 3);
    const int im = swz % mtiles, in = swz / mtiles;
    const int row0 = im * 256, col0 = in * 256;

    const int t = threadIdx.x;
    const int lane = t & 63;
    const int wid = t >> 6;
    const int wm = (wid >> 2) * 128;      // wave M base within tile
    const int wn = (wid & 3) * 64;        // wave N base within tile
    const int fr = lane & 15;
    const int g4 = lane >> 4;

    f32x4 acc[8][4];
#pragma unroll
    for (int m = 0; m < 8; ++m)
#pragma unroll
        for (int n = 0; n < 4; ++n) acc[m][n] = f32x4{0.f, 0.f, 0.f, 0.f};

    const int nt = K >> 6;
    const int srow = t >> 3;              // staging row within half (0..63)
    const int sc8  = t & 7;               // staging 16B-column (0..7)

    // stage one 128-row half (h=0/1) of a 256x64 tile into dst (linear LDS,
    // source pre-swizzled so that ds_read with col8^(row&7) sees logical data)
    auto stage_half = [&](const u16* __restrict__ g, int rowbase, int h, u16* dst) {
#pragma unroll
        for (int j = 0; j < 2; ++j) {
            const int rl = h * 128 + srow + j * 64;
            const int c8 = sc8 ^ (rl & 7);
            const u16* sp = g + (long)(rowbase + rl) * K + c8 * 8;
            __builtin_amdgcn_global_load_lds((gptr1_t)sp,
                (lptr3_t)(dst + rl * 64 + sc8 * 8), 16, 0, 0);
        }
    };

    // ---- prologue: tile0 (A h0,h1, B h0,h1)->buf0 ; tile1 (A h0,h1)->buf1 ----
    stage_half(A, row0, 0, smem);
    stage_half(A, row0, 1, smem);
    stage_half(B, col0, 0, smem + 16384);
    stage_half(B, col0, 1, smem + 16384);
    if (nt > 1) {
        stage_half(A + 64, row0, 0, smem + 32768);
        stage_half(A + 64, row0, 1, smem + 32768);
        WAITVM(4);                        // 12 issued, oldest 8 (= tile0) done
    } else {
        WAITVM(0);
    }
    barrier_fenced();

    short8v fa[4][2], fa2[4][2], fb[4][2];

    for (int tt = 0; tt < nt; ++tt) {
        u16* curA = smem + ((tt & 1) << 15);
        u16* curB = curA + 16384;
        u16* nxtA = smem + (((tt + 1) & 1) << 15);
        u16* nxtB = nxtA + 16384;
        const bool s1 = (tt + 1 < nt);
        const bool s2 = (tt + 2 < nt);

        // ---------------- phase 0 ----------------
#pragma unroll
        for (int m = 0; m < 4; ++m)
#pragma unroll
            for (int kk = 0; kk < 2; ++kk) {
                const int r = wm + m * 16 + fr;
                const int c8 = kk * 4 + g4;
                fa[m][kk] = *(const short8v*)(curA + r * 64 + ((c8 ^ (r & 7)) << 3));
            }
#pragma unroll
        for (int n = 0; n < 4; ++n)
#pragma unroll
            for (int kk = 0; kk < 2; ++kk) {
                const int r = wn + n * 16 + fr;
                const int c8 = kk * 4 + g4;
                fb[n][kk] = *(const short8v*)(curB + r * 64 + ((c8 ^ (r & 7)) << 3));
            }
        if (s1) stage_half(B + (tt + 1) * 64, col0, 0, nxtB);
        barrier_fenced();
        __builtin_amdgcn_s_setprio(1);
#pragma unroll
        for (int m = 0; m < 4; ++m)
#pragma unroll
            for (int n = 0; n < 4; ++n)
                acc[m][n] = __builtin_amdgcn_mfma_f32_16x16x32_bf16(fa[m][0], fb[n][0], acc[m][n], 0, 0, 0);
        __builtin_amdgcn_s_setprio(0);
        barrier_fenced();

        // ---------------- phase 1 ----------------
#pragma unroll
        for (int m = 0; m < 4; ++m)
#pragma unroll
            for (int kk = 0; kk < 2; ++kk) {
                const int r = wm + 64 + m * 16 + fr;
                const int c8 = kk * 4 + g4;
                fa2[m][kk] = *(const short8v*)(curA + r * 64 + ((c8 ^ (r & 7)) << 3));
            }
        if (s1) stage_half(B + (tt + 1) * 64, col0, 1, nxtB);
        barrier_fenced();
        __builtin_amdgcn_s_setprio(1);
#pragma unroll
        for (int m = 0; m < 4; ++m)
#pragma unroll
            for (int n = 0; n < 4; ++n)
                acc[m][n] = __builtin_amdgcn_mfma_f32_16x16x32_bf16(fa[m][1], fb[n][1], acc[m][n], 0, 0, 0);
        __builtin_amdgcn_s_setprio(0);
        barrier_fenced();

        // ---------------- phase 2 ----------------
        if (s2) stage_half(A + (tt + 2) * 64, row0, 0, curA);
        barrier_fenced();
        __builtin_amdgcn_s_setprio(1);
#pragma unroll
        for (int m = 0; m < 4; ++m)
#pragma unroll
            for (int n = 0; n < 4; ++n)
                acc[4 + m][n] = __builtin_amdgcn_mfma_f32_16x16x32_bf16(fa2[m][0], fb[n][0], acc[4 + m][n], 0, 0, 0);
        __builtin_amdgcn_s_setprio(0);
        barrier_fenced();

        // ---------------- phase 3 ----------------
        if (s2) stage_half(A + (tt + 2) * 64, row0, 1, curA);
        if (s1) { if (s2) { WAITVM(4); } else { WAITVM(0); } }
        barrier_fenced();
        __builtin_amdgcn_s_setprio(1);
#pragma unroll
        for (int m = 0; m < 4; ++m)
#pragma unroll
            for (int n = 0; n < 4; ++n)
                acc[4 + m][n] = __builtin_amdgcn_mfma_f32_16x16x32_bf16(fa2[m][1], fb[n][1], acc[4 + m][n], 0, 0, 0);
        __builtin_amdgcn_s_setprio(0);
        barrier_fenced();
    }

    // ---- epilogue: C/D layout col = lane&15, row = (lane>>4)*4 + reg ----
    const int rq = (lane >> 4) * 4;
    float bv[4];
#pragma unroll
    for (int n = 0; n < 4; ++n)
        bv[n] = bias ? bias[col0 + wn + n * 16 + fr] : 0.f;
#pragma unroll
    for (int m = 0; m < 8; ++m) {
#pragma unroll
        for (int n = 0; n < 4; ++n) {
            const int col = col0 + wn + n * 16 + fr;
#pragma unroll
            for (int r = 0; r < 4; ++r) {
                const int row = row0 + wm + m * 16 + rq + r;
                float v = alpha * acc[m][n][r] + bv[n];
                if (RELU) v = fmaxf(v, 0.f);
                if (OUTMODE == 0)
                    ((float*)Cp)[(long)row * N + col] = v;
                else
                    ((u16*)Cp)[(long)row * N + col] = f2bf(v);
            }
        }
    }
}

// ---------------------------------------------------------------------------
// GEMM (m97 structure) kept for ragged/batched shapes:
// C[M,N] = alpha * A[M,K] * B[N,K]^T + bias. 128x128 tile, BK=32, 4 waves.
// ---------------------------------------------------------------------------
template <int OUTMODE, int RELU>
__global__ __launch_bounds__(256) void gemm_bt(
    const u16* __restrict__ A, const u16* __restrict__ B,
    const float* __restrict__ bias, void* __restrict__ Cp,
    int M, int N, int K, int lda, int ldb, int ldc,
    int zi, long sAo, long sAi, long sBo, long sBi, long sCo, long sCi,
    float alpha)
{
    __shared__ u16 As[128 * 32];
    __shared__ u16 Bs[128 * 32];

    const int bz = blockIdx.z;
    A += (long)(bz / zi) * sAo + (long)(bz % zi) * sAi;
    B += (long)(bz / zi) * sBo + (long)(bz % zi) * sBi;
    const long offC = (long)(bz / zi) * sCo + (long)(bz % zi) * sCi;

    const int tm = blockIdx.x * 128;
    const int tn = blockIdx.y * 128;
    const int t = threadIdx.x;
    const int wave = t >> 6;
    const int lane = t & 63;
    const int wr = (wave >> 1) * 64;
    const int wc = (wave & 1) * 64;

    f32x4 acc[4][4];
#pragma unroll
    for (int m = 0; m < 4; ++m)
#pragma unroll
        for (int n = 0; n < 4; ++n) acc[m][n] = f32x4{0.f, 0.f, 0.f, 0.f};

    const int srow = t >> 2;
    const int scol = (t & 3) * 8;
    const int fr = lane & 15;
    const int kg = (lane >> 4) * 8;

    for (int k0 = 0; k0 < K; k0 += 32) {
        __syncthreads();
#pragma unroll
        for (int i = 0; i < 2; ++i) {
            int gr = tm + srow + i * 64; if (gr > M - 1) gr = M - 1;
            const u16* gp = A + (long)gr * lda + (k0 + scol);
            __builtin_amdgcn_global_load_lds((gptr1_t)gp, (lptr3_t)(As + i * 2048 + t * 8), 16, 0, 0);
        }
#pragma unroll
        for (int i = 0; i < 2; ++i) {
            int gr = tn + srow + i * 64; if (gr > N - 1) gr = N - 1;
            const u16* gp = B + (long)gr * ldb + (k0 + scol);
            __builtin_amdgcn_global_load_lds((gptr1_t)gp, (lptr3_t)(Bs + i * 2048 + t * 8), 16, 0, 0);
        }
        __syncthreads();

        short8v af[4], bf[4];
#pragma unroll
        for (int m = 0; m < 4; ++m)
            af[m] = *(const short8v*)(As + (wr + m * 16 + fr) * 32 + kg);
#pragma unroll
        for (int n = 0; n < 4; ++n)
            bf[n] = *(const short8v*)(Bs + (wc + n * 16 + fr) * 32 + kg);
#pragma unroll
        for (int m = 0; m < 4; ++m)
#pragma unroll
            for (int n = 0; n < 4; ++n)
                acc[m][n] = __builtin_amdgcn_mfma_f32_16x16x32_bf16(af[m], bf[n], acc[m][n], 0, 0, 0);
    }

    const int rq = (lane >> 4) * 4;
#pragma unroll
    for (int m = 0; m < 4; ++m) {
#pragma unroll
        for (int n = 0; n < 4; ++n) {
            const int col = tn + wc + n * 16 + fr;
            if (col >= N) continue;
            const float bv = bias ? bias[col] : 0.f;
#pragma unroll
            for (int r = 0; r < 4; ++r) {
                const int row = tm + wr + m * 16 + rq + r;
                if (row >= M) continue;
                float v = alpha * acc[m][n][r] + bv;
                if (RELU) v = v > 0.f ? v : 0.f;
                if (OUTMODE == 0)
                    ((float*)Cp)[offC + (long)row * ldc + col] = v;
                else
                    ((u16*)Cp)[offC + (long)row * ldc + col] = f2bf(v);
            }
        }
    }
}

// ---------------------------------------------------------------------------
// V transpose: vt[bh, d, k] = qkv[b, k, 2D + h*64 + d]  (bf16)
// ---------------------------------------------------------------------------
__global__ void transpose_v(const u16* __restrict__ qkv, u16* __restrict__ vt) {
    const int kt = blockIdx.x * 64;
    const int bh = blockIdx.y;
    const int b = bh >> 4, h = bh & 15;
    const int t = threadIdx.x;
    __shared__ u16 tile[64][72];
    const long src = (long)b * Sq * (3 * Dm) + 2 * Dm + h * HDm;
#pragma unroll
    for (int i = 0; i < 2; ++i) {
        const int kl = i * 32 + (t >> 3);
        const int d0 = (t & 7) * 8;
        short8v v = *(const short8v*)(qkv + src + (long)(kt + kl) * (3 * Dm) + d0);
        *(short8v*)(&tile[kl][d0]) = v;
    }
    __syncthreads();
#pragma unroll
    for (int i = 0; i < 2; ++i) {
        const int d = i * 32 + (t >> 3);
        const int kk0 = (t & 7) * 8;
        short8v o;
#pragma unroll
        for (int j = 0; j < 8; ++j) o[j] = (short)tile[kk0 + j][d];
        *(short8v*)(vt + ((long)bh * HDm + d) * Sq + kt + kk0) = o;
    }
}

// ---------------------------------------------------------------------------
// row softmax over 2048 bf16, in place.
// ---------------------------------------------------------------------------
__global__ void softmax_rows(u16* __restrict__ sc) {
    const long row = blockIdx.x;
    u16* p = sc + row * Sq;
    const int t = threadIdx.x;
    const int wave = t >> 6, lane = t & 63;
    __shared__ float rm[4], rsum[4];

    short8v v = *(const short8v*)(p + t * 8);
    float f[8];
#pragma unroll
    for (int j = 0; j < 8; ++j) f[j] = bf2f((u16)v[j]);
    float mx = f[0];
#pragma unroll
    for (int j = 1; j < 8; ++j) mx = fmaxf(mx, f[j]);
#pragma unroll
    for (int o = 32; o; o >>= 1) mx = fmaxf(mx, __shfl_xor(mx, o));
    if (lane == 0) rm[wave] = mx;
    __syncthreads();
    mx = fmaxf(fmaxf(rm[0], rm[1]), fmaxf(rm[2], rm[3]));

    float sum = 0.f;
#pragma unroll
    for (int j = 0; j < 8; ++j) { f[j] = __expf(f[j] - mx); sum += f[j]; }
#pragma unroll
    for (int o = 32; o; o >>= 1) sum += __shfl_xor(sum, o);
    if (lane == 0) rsum[wave] = sum;
    __syncthreads();
    sum = rsum[0] + rsum[1] + rsum[2] + rsum[3];
    const float inv = 1.f / sum;

    short8v o;
#pragma unroll
    for (int j = 0; j < 8; ++j) o[j] = (short)f2bf(f[j] * inv);
    *(short8v*)(p + t * 8) = o;
}

// ---------------------------------------------------------------------------
// residual + LayerNorm.
// ---------------------------------------------------------------------------
template <int W32>
__global__ void ln_kernel(float* __restrict__ x, const float* __restrict__ res,
                          const float* __restrict__ g, const float* __restrict__ be,
                          u16* __restrict__ out16) {
    const int row = blockIdx.x;
    const int t = threadIdx.x;
    const long base = (long)row * Dm + t * 4;
    float4 a = *(const float4*)(x + base);
    float4 b = *(const float4*)(res + base);
    float v0 = a.x + b.x, v1 = a.y + b.y, v2 = a.z + b.z, v3 = a.w + b.w;
    float s = v0 + v1 + v2 + v3;
    float q = v0 * v0 + v1 * v1 + v2 * v2 + v3 * v3;

    const int wave = t >> 6, lane = t & 63;
    __shared__ float rs[4], rq2[4];
#pragma unroll
    for (int o = 32; o; o >>= 1) { s += __shfl_xor(s, o); q += __shfl_xor(q, o); }
    if (lane == 0) { rs[wave] = s; rq2[wave] = q; }
    __syncthreads();
    s = rs[0] + rs[1] + rs[2] + rs[3];
    q = rq2[0] + rq2[1] + rq2[2] + rq2[3];

    const float mean = s * (1.f / Dm);
    const float var = q * (1.f / Dm) - mean * mean;
    const float rstd = rsqrtf(var + 1e-5f);
    const float4 gg = *(const float4*)(g + t * 4);
    const float4 bb = *(const float4*)(be + t * 4);
    float o0 = (v0 - mean) * rstd * gg.x + bb.x;
    float o1 = (v1 - mean) * rstd * gg.y + bb.y;
    float o2 = (v2 - mean) * rstd * gg.z + bb.z;
    float o3 = (v3 - mean) * rstd * gg.w + bb.w;
    U16x4 h = { f2bf(o0), f2bf(o1), f2bf(o2), f2bf(o3) };
    *(U16x4*)(out16 + base) = h;
    if (W32) {
        float4 ov = { o0, o1, o2, o3 };
        *(float4*)(x + base) = ov;
    }
}

// ---------------------------------------------------------------------------
extern "C" void kernel_launch(void* const* d_in, const int* in_sizes, int n_in,
                              void* d_out, int out_size, void* d_ws, size_t ws_size,
                              hipStream_t stream) {
    const int*   tokens = (const int*)  d_in[0];
    const float* emb    = (const float*)d_in[1];
    const float* pos    = (const float*)d_in[2];
    const float* w_qkv  = (const float*)d_in[3];
    const float* b_qkv  = (const float*)d_in[4];
    const float* w_o    = (const float*)d_in[5];
    const float* b_o    = (const float*)d_in[6];
    const float* g1     = (const float*)d_in[7];
    const float* beta1  = (const float*)d_in[8];
    const float* w1     = (const float*)d_in[9];
    const float* b1     = (const float*)d_in[10];
    const float* w2     = (const float*)d_in[11];
    const float* b2     = (const float*)d_in[12];
    const float* g2     = (const float*)d_in[13];
    const float* beta2  = (const float*)d_in[14];
    const float* w_fc   = (const float*)d_in[15];
    const float* b_fc   = (const float*)d_in[16];

    char* ws = (char*)d_ws;
    size_t off = 0;
    auto alloc = [&](size_t bytes) { void* p = ws + off; off += (bytes + 255) & ~(size_t)255; return p; };

    float* X32   = (float*)alloc((size_t)MTOK * Dm * 4);
    u16*   XB16  = (u16*)  alloc((size_t)MTOK * Dm * 2);
    u16*   QKV16 = (u16*)  alloc((size_t)MTOK * 3 * Dm * 2);
    u16*   VT16  = (u16*)  alloc((size_t)64 * HDm * Sq * 2);
    u16*   CTX16 = (u16*)  alloc((size_t)MTOK * Dm * 2);
    float* ATT32 = (float*)alloc((size_t)MTOK * Dm * 4);
    u16*   H16   = (u16*)  alloc((size_t)MTOK * DFFm * 2);
    u16*   WQ16  = (u16*)  alloc((size_t)3 * Dm * Dm * 2);
    u16*   WO16  = (u16*)  alloc((size_t)Dm * Dm * 2);
    u16*   W116  = (u16*)  alloc((size_t)DFFm * Dm * 2);
    u16*   W216  = (u16*)  alloc((size_t)Dm * DFFm * 2);
    u16*   WFC16 = (u16*)  alloc((size_t)Vv * Dm * 2);
    u16*   SC16  = (u16*)d_out;   // scores scratch: 64*2048*2048*2 = 537MB < d_out

    const dim3 blk(256);
    const dim3 blk512(512);

    // --- weight conversions ---
    to_bf16<<<1024, blk, 0, stream>>>(w_qkv, WQ16, (long)3 * Dm * Dm / 4);
    to_bf16<<<1024, blk, 0, stream>>>(w_o,   WO16, (long)Dm * Dm / 4);
    to_bf16<<<1024, blk, 0, stream>>>(w1,    W116, (long)DFFm * Dm / 4);
    to_bf16<<<1024, blk, 0, stream>>>(w2,    W216, (long)Dm * DFFm / 4);
    to_bf16<<<2048, blk, 0, stream>>>(w_fc,  WFC16, (long)Vv * Dm / 4);

    // --- embedding ---
    embed_kernel<<<MTOK, blk, 0, stream>>>(tokens, emb, pos, X32, XB16);

    // --- QKV projection: [8192,3072], K=1024 -> 256^2 8-phase (384 blocks) ---
    gemm256<1, 0><<<dim3((MTOK / 256) * ((3 * Dm) / 256)), blk512, 0, stream>>>(
        XB16, WQ16, b_qkv, QKV16, MTOK, 3 * Dm, Dm, 1.f, MTOK / 256);

    // --- V transpose for PV GEMM ---
    transpose_v<<<dim3(Sq / 64, Bz * Hh), blk, 0, stream>>>(QKV16, VT16);

    // --- scores = 0.125 * Q K^T per (b,h): M=N=2048, K=64, batch=64 ---
    gemm_bt<1, 0><<<dim3(Sq / 128, Sq / 128, Bz * Hh), blk, 0, stream>>>(
        QKV16, QKV16 + Dm, nullptr, SC16, Sq, Sq, HDm, 3 * Dm, 3 * Dm, Sq,
        Hh, (long)Sq * 3 * Dm, HDm, (long)Sq * 3 * Dm, HDm,
        (long)Hh * Sq * Sq, (long)Sq * Sq, 0.125f);

    // --- softmax in place ---
    softmax_rows<<<Bz * Hh * Sq, blk, 0, stream>>>(SC16);

    // --- ctx = P V per (b,h): M=2048, N=64, K=2048 ---
    gemm_bt<1, 0><<<dim3(Sq / 128, 1, Bz * Hh), blk, 0, stream>>>(
        SC16, VT16, nullptr, CTX16, Sq, HDm, Sq, Sq, Sq, Dm,
        Hh, (long)Hh * Sq * Sq, (long)Sq * Sq,
        (long)Hh * HDm * Sq, (long)HDm * Sq,
        (long)Sq * Dm, (long)HDm, 1.f);

    // --- attn_out = ctx @ w_o^T + b_o (fp32) ---
    gemm_bt<0, 0><<<dim3(MTOK / 128, Dm / 128, 1), blk, 0, stream>>>(
        CTX16, WO16, b_o, ATT32, MTOK, Dm, Dm, Dm, Dm, Dm,
        1, 0, 0, 0, 0, 0, 0, 1.f);

    // --- LN1 ---
    ln_kernel<1><<<MTOK, blk, 0, stream>>>(X32, ATT32, g1, beta1, XB16);

    // --- FFN1: h = relu(x1 @ w1^T + b1), [8192,4096] K=1024 -> 256^2 (512 blocks) ---
    gemm256<1, 1><<<dim3((MTOK / 256) * (DFFm / 256)), blk512, 0, stream>>>(
        XB16, W116, b1, H16, MTOK, DFFm, Dm, 1.f, MTOK / 256);

    // --- FFN2: ffn = h @ w2^T + b2 (fp32 into ATT32), K=4096 ---
    gemm_bt<0, 0><<<dim3(MTOK / 128, Dm / 128, 1), blk, 0, stream>>>(
        H16, W216, b2, ATT32, MTOK, Dm, DFFm, DFFm, DFFm, Dm,
        1, 0, 0, 0, 0, 0, 0, 1.f);

    // --- LN2 ---
    ln_kernel<0><<<MTOK, blk, 0, stream>>>(X32, ATT32, g2, beta2, XB16);

    // --- final vocab projection: [8192,32000] K=1024 -> 256^2 (4000 blocks) ---
    gemm256<0, 0><<<dim3((MTOK / 256) * (Vv / 256)), blk512, 0, stream>>>(
        XB16, WFC16, b_fc, (float*)d_out, MTOK, Vv, Dm, 1.f, MTOK / 256);
}

// Round 3
// 1799.503 us; speedup vs baseline: 1.2555x; 1.0217x over previous
//
#include <hip/hip_runtime.h>
#include <stdint.h>

#define Bz   4
#define Sq   2048
#define Dm   1024
#define Hh   16
#define HDm  64
#define DFFm 4096
#define Vv   32000
#define MTOK (Bz * Sq)   // 8192

typedef unsigned short u16;
typedef __attribute__((ext_vector_type(8))) short short8v;   // 8 bf16 = 4 VGPR (MFMA frag)
typedef __attribute__((ext_vector_type(4))) float f32x4;

struct alignas(8) U16x4 { u16 x, y, z, w; };

typedef const __attribute__((address_space(1))) void* gptr1_t;
typedef __attribute__((address_space(3))) void* lptr3_t;

__device__ __forceinline__ u16 f2bf(float f) {
    union { float f; unsigned u; } v; v.f = f;
    unsigned r = v.u + 0x7FFF + ((v.u >> 16) & 1);   // RNE
    return (u16)(r >> 16);
}
__device__ __forceinline__ float bf2f(u16 h) {
    union { unsigned u; float f; } v; v.u = ((unsigned)h) << 16;
    return v.f;
}

#define WAITVM(N) asm volatile("s_waitcnt vmcnt(" #N ")" ::: "memory")

__device__ __forceinline__ void barrier_fenced() {
    asm volatile("" ::: "memory");
    __builtin_amdgcn_s_barrier();
    asm volatile("" ::: "memory");
}

// ---------------------------------------------------------------------------
// fp32 -> bf16 conversion (vectorized, grid-stride)
// ---------------------------------------------------------------------------
__global__ void to_bf16(const float* __restrict__ in, u16* __restrict__ out, long n4) {
    long i = (long)blockIdx.x * blockDim.x + threadIdx.x;
    const long stride = (long)gridDim.x * blockDim.x;
    for (; i < n4; i += stride) {
        float4 v = *(const float4*)(in + i * 4);
        U16x4 h = { f2bf(v.x), f2bf(v.y), f2bf(v.z), f2bf(v.w) };
        *(U16x4*)(out + i * 4) = h;
    }
}

// ---------------------------------------------------------------------------
// embedding + positional: x = emb[tok] + pos ; writes fp32 and bf16 copies
// ---------------------------------------------------------------------------
__global__ void embed_kernel(const int* __restrict__ tok, const float* __restrict__ emb,
                             const float* __restrict__ pos, float* __restrict__ x32,
                             u16* __restrict__ x16) {
    const int row = blockIdx.x;            // b*S + s
    const int s = row & (Sq - 1);
    const int t = threadIdx.x;             // 256 threads * 4 floats = 1024
    const long tokid = tok[row];
    float4 e = *(const float4*)(emb + tokid * Dm + t * 4);
    float4 p = *(const float4*)(pos + (long)s * Dm + t * 4);
    float4 v = { e.x + p.x, e.y + p.y, e.z + p.z, e.w + p.w };
    const long base = (long)row * Dm + t * 4;
    *(float4*)(x32 + base) = v;
    U16x4 h = { f2bf(v.x), f2bf(v.y), f2bf(v.z), f2bf(v.w) };
    *(U16x4*)(x16 + base) = h;
}

// ===========================================================================
// 256x256 8-barrier/K-tile GEMM, template-faithful phase interleave.
// C[M,N] = alpha*A[M,K]*B[N,K]^T + bias.  M%256==0, N%256==0, K%64==0,
// nt=K/64 >= 3, grid %8 == 0.  512 threads = 8 waves as 4M x 2N
// (per-wave output 64 x 128).  BK=64, MFMA 16x16x32.
// LDS 160 KiB: A double-buffer (2x32KB) + B triple-buffer (3x32KB).
//   - A(t+1) staged distance-1 into Ab[(t+1)&1]  (never the read buffer)
//   - B(t+2) staged distance-2 into Bb[(t+2)%3]  (never a read buffer)
// Phases per K-tile (2 barriers each):
//   p0: rd fa[.]kk0 + fbl[.]kk0 (8 ds_read); stage A(t+1).h0; MFMA n0-3 kk0
//   p1: rd fa[.]kk1 + fbl[.]kk1 (8);         stage A(t+1).h1; MFMA n0-3 kk1
//   p2: rd fbh[.]kk0 (4);                    stage B(t+2).h0; MFMA n4-7 kk0
//   p3: rd fbh[.]kk1 (4);                    stage B(t+2).h1; vmcnt(4);
//       MFMA n4-7 kk1
// vmcnt(4) sits BEFORE p3's closing barrier so the barrier publishes every
// wave's LDS writes for tile t+1; 4 loads (B(t+2) half) stay in flight.
// XOR swizzle col8 ^= row&7 on both gload_lds source and ds_read (rule #21).
// ===========================================================================
template <int OUTMODE, int RELU>
__global__ __launch_bounds__(512, 2) void gemm256(
    const u16* __restrict__ A, const u16* __restrict__ B,
    const float* __restrict__ bias, void* __restrict__ Cp,
    int M, int N, int K, float alpha, int mtiles)
{
    __shared__ u16 smem[81920];   // 160 KiB

    // bijective XCD swizzle (grid % 8 == 0)
    const int nwg = gridDim.x;
    const int bid = blockIdx.x;
    const int cpx = nwg >> 3;
    const int swz = (bid & 7) * cpx + (bid >> 3);
    const int im = swz % mtiles, in = swz / mtiles;
    const int row0 = im * 256, col0 = in * 256;

    const int t = threadIdx.x;
    const int lane = t & 63;
    const int wid = t >> 6;
    const int wm = (wid >> 1) * 64;       // 4 M-groups x 64 rows
    const int wn = (wid & 1) * 128;       // 2 N-groups x 128 cols
    const int fr = lane & 15;
    const int g4 = lane >> 4;

    f32x4 acc[4][8];
#pragma unroll
    for (int m = 0; m < 4; ++m)
#pragma unroll
        for (int n = 0; n < 8; ++n) acc[m][n] = f32x4{0.f, 0.f, 0.f, 0.f};

    const int nt = K >> 6;
    const int srow = t >> 3;              // staging row (0..63) within 64-row unit
    const int sc8  = t & 7;               // staging 16B column

    auto stage_half = [&](const u16* __restrict__ g, int rowbase, int h, u16* dst) {
#pragma unroll
        for (int j = 0; j < 2; ++j) {
            const int rl = h * 128 + srow + j * 64;
            const int c8 = sc8 ^ (rl & 7);
            const u16* sp = g + (long)(rowbase + rl) * K + c8 * 8;
            __builtin_amdgcn_global_load_lds((gptr1_t)sp,
                (lptr3_t)(dst + rl * 64 + sc8 * 8), 16, 0, 0);
        }
    };

    auto rdA = [&](const u16* base, int kk, int m) -> short8v {
        const int r = wm + m * 16 + fr;
        const int c8 = kk * 4 + g4;
        return *(const short8v*)(base + r * 64 + ((c8 ^ (r & 7)) << 3));
    };
    auto rdB = [&](const u16* base, int kk, int n) -> short8v {
        const int r = wn + n * 16 + fr;
        const int c8 = kk * 4 + g4;
        return *(const short8v*)(base + r * 64 + ((c8 ^ (r & 7)) << 3));
    };

    // ---- prologue: A(0)->Ab0, B(0)->Bb0, B(1)->Bb1 (12 loads) ----
    stage_half(A, row0, 0, smem);
    stage_half(A, row0, 1, smem);
    stage_half(B, col0, 0, smem + 32768);
    stage_half(B, col0, 1, smem + 32768);
    if (nt > 1) {
        stage_half(B + 64, col0, 0, smem + 49152);
        stage_half(B + 64, col0, 1, smem + 49152);
        WAITVM(4);                        // A(0),B(0) resident; B(1) in flight
    } else {
        WAITVM(0);
    }
    barrier_fenced();

    short8v fa[4][2], fbl[4][2], fbh[4][2];

    for (int tt = 0; tt < nt; ++tt) {
        u16* rA = smem + ((tt & 1) << 14);
        u16* rB = smem + 32768 + ((unsigned)tt % 3u) * 16384;
        u16* sA = smem + ((~tt & 1) << 14);
        u16* sB = smem + 32768 + ((unsigned)(tt + 2) % 3u) * 16384;
        const bool stA = (tt + 1 < nt);
        const bool stB = (tt + 2 < nt);

        // ---------------- phase 0 ----------------
#pragma unroll
        for (int m = 0; m < 4; ++m) fa[m][0] = rdA(rA, 0, m);
#pragma unroll
        for (int n = 0; n < 4; ++n) fbl[n][0] = rdB(rB, 0, n);
        if (stA) stage_half(A + (tt + 1) * 64, row0, 0, sA);
        barrier_fenced();
        asm volatile("s_waitcnt lgkmcnt(0)" ::: "memory");
        __builtin_amdgcn_s_setprio(1);
#pragma unroll
        for (int m = 0; m < 4; ++m)
#pragma unroll
            for (int n = 0; n < 4; ++n)
                acc[m][n] = __builtin_amdgcn_mfma_f32_16x16x32_bf16(fa[m][0], fbl[n][0], acc[m][n], 0, 0, 0);
        __builtin_amdgcn_s_setprio(0);
        barrier_fenced();

        // ---------------- phase 1 ----------------
#pragma unroll
        for (int m = 0; m < 4; ++m) fa[m][1] = rdA(rA, 1, m);
#pragma unroll
        for (int n = 0; n < 4; ++n) fbl[n][1] = rdB(rB, 1, n);
        if (stA) stage_half(A + (tt + 1) * 64, row0, 1, sA);
        barrier_fenced();
        asm volatile("s_waitcnt lgkmcnt(0)" ::: "memory");
        __builtin_amdgcn_s_setprio(1);
#pragma unroll
        for (int m = 0; m < 4; ++m)
#pragma unroll
            for (int n = 0; n < 4; ++n)
                acc[m][n] = __builtin_amdgcn_mfma_f32_16x16x32_bf16(fa[m][1], fbl[n][1], acc[m][n], 0, 0, 0);
        __builtin_amdgcn_s_setprio(0);
        barrier_fenced();

        // ---------------- phase 2 ----------------
#pragma unroll
        for (int n = 0; n < 4; ++n) fbh[n][0] = rdB(rB, 0, n + 4);
        if (stB) stage_half(B + (tt + 2) * 64, col0, 0, sB);
        barrier_fenced();
        asm volatile("s_waitcnt lgkmcnt(0)" ::: "memory");
        __builtin_amdgcn_s_setprio(1);
#pragma unroll
        for (int m = 0; m < 4; ++m)
#pragma unroll
            for (int n = 0; n < 4; ++n)
                acc[m][n + 4] = __builtin_amdgcn_mfma_f32_16x16x32_bf16(fa[m][0], fbh[n][0], acc[m][n + 4], 0, 0, 0);
        __builtin_amdgcn_s_setprio(0);
        barrier_fenced();

        // ---------------- phase 3 ----------------
#pragma unroll
        for (int n = 0; n < 4; ++n) fbh[n][1] = rdB(rB, 1, n + 4);
        if (stB) stage_half(B + (tt + 2) * 64, col0, 1, sB);
        if (tt + 2 < nt) { WAITVM(4); } else { WAITVM(0); }
        barrier_fenced();
        asm volatile("s_waitcnt lgkmcnt(0)" ::: "memory");
        __builtin_amdgcn_s_setprio(1);
#pragma unroll
        for (int m = 0; m < 4; ++m)
#pragma unroll
            for (int n = 0; n < 4; ++n)
                acc[m][n + 4] = __builtin_amdgcn_mfma_f32_16x16x32_bf16(fa[m][1], fbh[n][1], acc[m][n + 4], 0, 0, 0);
        __builtin_amdgcn_s_setprio(0);
        barrier_fenced();
    }

    // ---- epilogue: C/D layout col = lane&15, row = (lane>>4)*4 + reg ----
    const int rq = (lane >> 4) * 4;
    float bv[8];
#pragma unroll
    for (int n = 0; n < 8; ++n)
        bv[n] = bias ? bias[col0 + wn + n * 16 + fr] : 0.f;
#pragma unroll
    for (int m = 0; m < 4; ++m) {
#pragma unroll
        for (int n = 0; n < 8; ++n) {
            const int col = col0 + wn + n * 16 + fr;
#pragma unroll
            for (int r = 0; r < 4; ++r) {
                const int row = row0 + wm + m * 16 + rq + r;
                float v = alpha * acc[m][n][r] + bv[n];
                if (RELU) v = fmaxf(v, 0.f);
                if (OUTMODE == 0)
                    ((float*)Cp)[(long)row * N + col] = v;
                else
                    ((u16*)Cp)[(long)row * N + col] = f2bf(v);
            }
        }
    }
}

// ---------------------------------------------------------------------------
// GEMM (m97 structure) kept for ragged/batched shapes (scores, PV):
// C[M,N] = alpha * A[M,K] * B[N,K]^T + bias. 128x128 tile, BK=32, 4 waves.
// ---------------------------------------------------------------------------
template <int OUTMODE, int RELU>
__global__ __launch_bounds__(256) void gemm_bt(
    const u16* __restrict__ A, const u16* __restrict__ B,
    const float* __restrict__ bias, void* __restrict__ Cp,
    int M, int N, int K, int lda, int ldb, int ldc,
    int zi, long sAo, long sAi, long sBo, long sBi, long sCo, long sCi,
    float alpha)
{
    __shared__ u16 As[128 * 32];
    __shared__ u16 Bs[128 * 32];

    const int bz = blockIdx.z;
    A += (long)(bz / zi) * sAo + (long)(bz % zi) * sAi;
    B += (long)(bz / zi) * sBo + (long)(bz % zi) * sBi;
    const long offC = (long)(bz / zi) * sCo + (long)(bz % zi) * sCi;

    const int tm = blockIdx.x * 128;
    const int tn = blockIdx.y * 128;
    const int t = threadIdx.x;
    const int wave = t >> 6;
    const int lane = t & 63;
    const int wr = (wave >> 1) * 64;
    const int wc = (wave & 1) * 64;

    f32x4 acc[4][4];
#pragma unroll
    for (int m = 0; m < 4; ++m)
#pragma unroll
        for (int n = 0; n < 4; ++n) acc[m][n] = f32x4{0.f, 0.f, 0.f, 0.f};

    const int srow = t >> 2;
    const int scol = (t & 3) * 8;
    const int fr = lane & 15;
    const int kg = (lane >> 4) * 8;

    for (int k0 = 0; k0 < K; k0 += 32) {
        __syncthreads();
#pragma unroll
        for (int i = 0; i < 2; ++i) {
            int gr = tm + srow + i * 64; if (gr > M - 1) gr = M - 1;
            const u16* gp = A + (long)gr * lda + (k0 + scol);
            __builtin_amdgcn_global_load_lds((gptr1_t)gp, (lptr3_t)(As + i * 2048 + t * 8), 16, 0, 0);
        }
#pragma unroll
        for (int i = 0; i < 2; ++i) {
            int gr = tn + srow + i * 64; if (gr > N - 1) gr = N - 1;
            const u16* gp = B + (long)gr * ldb + (k0 + scol);
            __builtin_amdgcn_global_load_lds((gptr1_t)gp, (lptr3_t)(Bs + i * 2048 + t * 8), 16, 0, 0);
        }
        __syncthreads();

        short8v af[4], bf[4];
#pragma unroll
        for (int m = 0; m < 4; ++m)
            af[m] = *(const short8v*)(As + (wr + m * 16 + fr) * 32 + kg);
#pragma unroll
        for (int n = 0; n < 4; ++n)
            bf[n] = *(const short8v*)(Bs + (wc + n * 16 + fr) * 32 + kg);
#pragma unroll
        for (int m = 0; m < 4; ++m)
#pragma unroll
            for (int n = 0; n < 4; ++n)
                acc[m][n] = __builtin_amdgcn_mfma_f32_16x16x32_bf16(af[m], bf[n], acc[m][n], 0, 0, 0);
    }

    const int rq = (lane >> 4) * 4;
#pragma unroll
    for (int m = 0; m < 4; ++m) {
#pragma unroll
        for (int n = 0; n < 4; ++n) {
            const int col = tn + wc + n * 16 + fr;
            if (col >= N) continue;
            const float bv = bias ? bias[col] : 0.f;
#pragma unroll
            for (int r = 0; r < 4; ++r) {
                const int row = tm + wr + m * 16 + rq + r;
                if (row >= M) continue;
                float v = alpha * acc[m][n][r] + bv;
                if (RELU) v = v > 0.f ? v : 0.f;
                if (OUTMODE == 0)
                    ((float*)Cp)[offC + (long)row * ldc + col] = v;
                else
                    ((u16*)Cp)[offC + (long)row * ldc + col] = f2bf(v);
            }
        }
    }
}

// ---------------------------------------------------------------------------
// V transpose: vt[bh, d, k] = qkv[b, k, 2D + h*64 + d]  (bf16)
// ---------------------------------------------------------------------------
__global__ void transpose_v(const u16* __restrict__ qkv, u16* __restrict__ vt) {
    const int kt = blockIdx.x * 64;
    const int bh = blockIdx.y;
    const int b = bh >> 4, h = bh & 15;
    const int t = threadIdx.x;
    __shared__ u16 tile[64][72];
    const long src = (long)b * Sq * (3 * Dm) + 2 * Dm + h * HDm;
#pragma unroll
    for (int i = 0; i < 2; ++i) {
        const int kl = i * 32 + (t >> 3);
        const int d0 = (t & 7) * 8;
        short8v v = *(const short8v*)(qkv + src + (long)(kt + kl) * (3 * Dm) + d0);
        *(short8v*)(&tile[kl][d0]) = v;
    }
    __syncthreads();
#pragma unroll
    for (int i = 0; i < 2; ++i) {
        const int d = i * 32 + (t >> 3);
        const int kk0 = (t & 7) * 8;
        short8v o;
#pragma unroll
        for (int j = 0; j < 8; ++j) o[j] = (short)tile[kk0 + j][d];
        *(short8v*)(vt + ((long)bh * HDm + d) * Sq + kt + kk0) = o;
    }
}

// ---------------------------------------------------------------------------
// row softmax over 2048 bf16, in place.
// ---------------------------------------------------------------------------
__global__ void softmax_rows(u16* __restrict__ sc) {
    const long row = blockIdx.x;
    u16* p = sc + row * Sq;
    const int t = threadIdx.x;
    const int wave = t >> 6, lane = t & 63;
    __shared__ float rm[4], rsum[4];

    short8v v = *(const short8v*)(p + t * 8);
    float f[8];
#pragma unroll
    for (int j = 0; j < 8; ++j) f[j] = bf2f((u16)v[j]);
    float mx = f[0];
#pragma unroll
    for (int j = 1; j < 8; ++j) mx = fmaxf(mx, f[j]);
#pragma unroll
    for (int o = 32; o; o >>= 1) mx = fmaxf(mx, __shfl_xor(mx, o));
    if (lane == 0) rm[wave] = mx;
    __syncthreads();
    mx = fmaxf(fmaxf(rm[0], rm[1]), fmaxf(rm[2], rm[3]));

    float sum = 0.f;
#pragma unroll
    for (int j = 0; j < 8; ++j) { f[j] = __expf(f[j] - mx); sum += f[j]; }
#pragma unroll
    for (int o = 32; o; o >>= 1) sum += __shfl_xor(sum, o);
    if (lane == 0) rsum[wave] = sum;
    __syncthreads();
    sum = rsum[0] + rsum[1] + rsum[2] + rsum[3];
    const float inv = 1.f / sum;

    short8v o;
#pragma unroll
    for (int j = 0; j < 8; ++j) o[j] = (short)f2bf(f[j] * inv);
    *(short8v*)(p + t * 8) = o;
}

// ---------------------------------------------------------------------------
// residual + LayerNorm.
// ---------------------------------------------------------------------------
template <int W32>
__global__ void ln_kernel(float* __restrict__ x, const float* __restrict__ res,
                          const float* __restrict__ g, const float* __restrict__ be,
                          u16* __restrict__ out16) {
    const int row = blockIdx.x;
    const int t = threadIdx.x;
    const long base = (long)row * Dm + t * 4;
    float4 a = *(const float4*)(x + base);
    float4 b = *(const float4*)(res + base);
    float v0 = a.x + b.x, v1 = a.y + b.y, v2 = a.z + b.z, v3 = a.w + b.w;
    float s = v0 + v1 + v2 + v3;
    float q = v0 * v0 + v1 * v1 + v2 * v2 + v3 * v3;

    const int wave = t >> 6, lane = t & 63;
    __shared__ float rs[4], rq2[4];
#pragma unroll
    for (int o = 32; o; o >>= 1) { s += __shfl_xor(s, o); q += __shfl_xor(q, o); }
    if (lane == 0) { rs[wave] = s; rq2[wave] = q; }
    __syncthreads();
    s = rs[0] + rs[1] + rs[2] + rs[3];
    q = rq2[0] + rq2[1] + rq2[2] + rq2[3];

    const float mean = s * (1.f / Dm);
    const float var = q * (1.f / Dm) - mean * mean;
    const float rstd = rsqrtf(var + 1e-5f);
    const float4 gg = *(const float4*)(g + t * 4);
    const float4 bb = *(const float4*)(be + t * 4);
    float o0 = (v0 - mean) * rstd * gg.x + bb.x;
    float o1 = (v1 - mean) * rstd * gg.y + bb.y;
    float o2 = (v2 - mean) * rstd * gg.z + bb.z;
    float o3 = (v3 - mean) * rstd * gg.w + bb.w;
    U16x4 h = { f2bf(o0), f2bf(o1), f2bf(o2), f2bf(o3) };
    *(U16x4*)(out16 + base) = h;
    if (W32) {
        float4 ov = { o0, o1, o2, o3 };
        *(float4*)(x + base) = ov;
    }
}

// ---------------------------------------------------------------------------
extern "C" void kernel_launch(void* const* d_in, const int* in_sizes, int n_in,
                              void* d_out, int out_size, void* d_ws, size_t ws_size,
                              hipStream_t stream) {
    const int*   tokens = (const int*)  d_in[0];
    const float* emb    = (const float*)d_in[1];
    const float* pos    = (const float*)d_in[2];
    const float* w_qkv  = (const float*)d_in[3];
    const float* b_qkv  = (const float*)d_in[4];
    const float* w_o    = (const float*)d_in[5];
    const float* b_o    = (const float*)d_in[6];
    const float* g1     = (const float*)d_in[7];
    const float* beta1  = (const float*)d_in[8];
    const float* w1     = (const float*)d_in[9];
    const float* b1     = (const float*)d_in[10];
    const float* w2     = (const float*)d_in[11];
    const float* b2     = (const float*)d_in[12];
    const float* g2     = (const float*)d_in[13];
    const float* beta2  = (const float*)d_in[14];
    const float* w_fc   = (const float*)d_in[15];
    const float* b_fc   = (const float*)d_in[16];

    char* ws = (char*)d_ws;
    size_t off = 0;
    auto alloc = [&](size_t bytes) { void* p = ws + off; off += (bytes + 255) & ~(size_t)255; return p; };

    float* X32   = (float*)alloc((size_t)MTOK * Dm * 4);
    u16*   XB16  = (u16*)  alloc((size_t)MTOK * Dm * 2);
    u16*   QKV16 = (u16*)  alloc((size_t)MTOK * 3 * Dm * 2);
    u16*   VT16  = (u16*)  alloc((size_t)64 * HDm * Sq * 2);
    u16*   CTX16 = (u16*)  alloc((size_t)MTOK * Dm * 2);
    float* ATT32 = (float*)alloc((size_t)MTOK * Dm * 4);
    u16*   H16   = (u16*)  alloc((size_t)MTOK * DFFm * 2);
    u16*   WQ16  = (u16*)  alloc((size_t)3 * Dm * Dm * 2);
    u16*   WO16  = (u16*)  alloc((size_t)Dm * Dm * 2);
    u16*   W116  = (u16*)  alloc((size_t)DFFm * Dm * 2);
    u16*   W216  = (u16*)  alloc((size_t)Dm * DFFm * 2);
    u16*   WFC16 = (u16*)  alloc((size_t)Vv * Dm * 2);
    u16*   SC16  = (u16*)d_out;   // scores scratch: 64*2048*2048*2 = 537MB < d_out

    const dim3 blk(256);
    const dim3 blk512(512);

    // --- weight conversions ---
    to_bf16<<<1024, blk, 0, stream>>>(w_qkv, WQ16, (long)3 * Dm * Dm / 4);
    to_bf16<<<1024, blk, 0, stream>>>(w_o,   WO16, (long)Dm * Dm / 4);
    to_bf16<<<1024, blk, 0, stream>>>(w1,    W116, (long)DFFm * Dm / 4);
    to_bf16<<<1024, blk, 0, stream>>>(w2,    W216, (long)Dm * DFFm / 4);
    to_bf16<<<2048, blk, 0, stream>>>(w_fc,  WFC16, (long)Vv * Dm / 4);

    // --- embedding ---
    embed_kernel<<<MTOK, blk, 0, stream>>>(tokens, emb, pos, X32, XB16);

    // --- QKV projection: [8192,3072], K=1024 (384 blocks) ---
    gemm256<1, 0><<<dim3((MTOK / 256) * ((3 * Dm) / 256)), blk512, 0, stream>>>(
        XB16, WQ16, b_qkv, QKV16, MTOK, 3 * Dm, Dm, 1.f, MTOK / 256);

    // --- V transpose for PV GEMM ---
    transpose_v<<<dim3(Sq / 64, Bz * Hh), blk, 0, stream>>>(QKV16, VT16);

    // --- scores = 0.125 * Q K^T per (b,h): M=N=2048, K=64, batch=64 ---
    gemm_bt<1, 0><<<dim3(Sq / 128, Sq / 128, Bz * Hh), blk, 0, stream>>>(
        QKV16, QKV16 + Dm, nullptr, SC16, Sq, Sq, HDm, 3 * Dm, 3 * Dm, Sq,
        Hh, (long)Sq * 3 * Dm, HDm, (long)Sq * 3 * Dm, HDm,
        (long)Hh * Sq * Sq, (long)Sq * Sq, 0.125f);

    // --- softmax in place ---
    softmax_rows<<<Bz * Hh * Sq, blk, 0, stream>>>(SC16);

    // --- ctx = P V per (b,h): M=2048, N=64, K=2048 ---
    gemm_bt<1, 0><<<dim3(Sq / 128, 1, Bz * Hh), blk, 0, stream>>>(
        SC16, VT16, nullptr, CTX16, Sq, HDm, Sq, Sq, Sq, Dm,
        Hh, (long)Hh * Sq * Sq, (long)Sq * Sq,
        (long)Hh * HDm * Sq, (long)HDm * Sq,
        (long)Sq * Dm, (long)HDm, 1.f);

    // --- attn_out = ctx @ w_o^T + b_o (fp32), [8192,1024] K=1024 (128 blocks) ---
    gemm256<0, 0><<<dim3((MTOK / 256) * (Dm / 256)), blk512, 0, stream>>>(
        CTX16, WO16, b_o, ATT32, MTOK, Dm, Dm, 1.f, MTOK / 256);

    // --- LN1 ---
    ln_kernel<1><<<MTOK, blk, 0, stream>>>(X32, ATT32, g1, beta1, XB16);

    // --- FFN1: h = relu(x1 @ w1^T + b1), [8192,4096] K=1024 (512 blocks) ---
    gemm256<1, 1><<<dim3((MTOK / 256) * (DFFm / 256)), blk512, 0, stream>>>(
        XB16, W116, b1, H16, MTOK, DFFm, Dm, 1.f, MTOK / 256);

    // --- FFN2: ffn = h @ w2^T + b2 (fp32), [8192,1024] K=4096 (128 blocks) ---
    gemm256<0, 0><<<dim3((MTOK / 256) * (Dm / 256)), blk512, 0, stream>>>(
        H16, W216, b2, ATT32, MTOK, Dm, DFFm, 1.f, MTOK / 256);

    // --- LN2 ---
    ln_kernel<0><<<MTOK, blk, 0, stream>>>(X32, ATT32, g2, beta2, XB16);

    // --- final vocab projection: [8192,32000] K=1024 (4000 blocks) ---
    gemm256<0, 0><<<dim3((MTOK / 256) * (Vv / 256)), blk512, 0, stream>>>(
        XB16, WFC16, b_fc, (float*)d_out, MTOK, Vv, Dm, 1.f, MTOK / 256);
}

// Round 4
// 1297.039 us; speedup vs baseline: 1.7418x; 1.3874x over previous
//
#include <hip/hip_runtime.h>
#include <stdint.h>

#define Bz   4
#define Sq   2048
#define Dm   1024
#define Hh   16
#define HDm  64
#define DFFm 4096
#define Vv   32000
#define MTOK (Bz * Sq)   // 8192

typedef unsigned short u16;
typedef __attribute__((ext_vector_type(8))) short short8v;   // 8 bf16 = 4 VGPR (MFMA frag)
typedef __attribute__((ext_vector_type(4))) float f32x4;

struct alignas(8) U16x4 { u16 x, y, z, w; };

typedef const __attribute__((address_space(1))) void* gptr1_t;
typedef __attribute__((address_space(3))) void* lptr3_t;

__device__ __forceinline__ u16 f2bf(float f) {
    union { float f; unsigned u; } v; v.f = f;
    unsigned r = v.u + 0x7FFF + ((v.u >> 16) & 1);   // RNE
    return (u16)(r >> 16);
}
__device__ __forceinline__ float bf2f(u16 h) {
    union { unsigned u; float f; } v; v.u = ((unsigned)h) << 16;
    return v.f;
}

#define WAITVM(N) asm volatile("s_waitcnt vmcnt(" #N ")" ::: "memory")

__device__ __forceinline__ void barrier_fenced() {
    asm volatile("" ::: "memory");
    __builtin_amdgcn_s_barrier();
    asm volatile("" ::: "memory");
}

// ---------------------------------------------------------------------------
// fp32 -> bf16 conversion (vectorized, grid-stride)
// ---------------------------------------------------------------------------
__global__ void to_bf16(const float* __restrict__ in, u16* __restrict__ out, long n4) {
    long i = (long)blockIdx.x * blockDim.x + threadIdx.x;
    const long stride = (long)gridDim.x * blockDim.x;
    for (; i < n4; i += stride) {
        float4 v = *(const float4*)(in + i * 4);
        U16x4 h = { f2bf(v.x), f2bf(v.y), f2bf(v.z), f2bf(v.w) };
        *(U16x4*)(out + i * 4) = h;
    }
}

// ---------------------------------------------------------------------------
// embedding + positional: x = emb[tok] + pos ; writes fp32 and bf16 copies
// ---------------------------------------------------------------------------
__global__ void embed_kernel(const int* __restrict__ tok, const float* __restrict__ emb,
                             const float* __restrict__ pos, float* __restrict__ x32,
                             u16* __restrict__ x16) {
    const int row = blockIdx.x;            // b*S + s
    const int s = row & (Sq - 1);
    const int t = threadIdx.x;             // 256 threads * 4 floats = 1024
    const long tokid = tok[row];
    float4 e = *(const float4*)(emb + tokid * Dm + t * 4);
    float4 p = *(const float4*)(pos + (long)s * Dm + t * 4);
    float4 v = { e.x + p.x, e.y + p.y, e.z + p.z, e.w + p.w };
    const long base = (long)row * Dm + t * 4;
    *(float4*)(x32 + base) = v;
    U16x4 h = { f2bf(v.x), f2bf(v.y), f2bf(v.z), f2bf(v.w) };
    *(U16x4*)(x16 + base) = h;
}

// ===========================================================================
// 256x256 8-barrier/K-tile GEMM (r3 structure, unchanged except NT stores).
// C[M,N] = alpha*A[M,K]*B[N,K]^T + bias.  M%256==0, N%256==0, K%64==0,
// nt=K/64 >= 3, grid %8 == 0.  512 threads = 8 waves as 4M x 2N.
// LDS 160 KiB: A dbuf (2x32KB) + B tribuf (3x32KB); A dist-1, B dist-2
// prefetch; single vmcnt(4) per K-tile before the p3 closing barrier.
// NT=1: non-temporal C stores (bypass L3 so A/B panels stay resident).
// ===========================================================================
template <int OUTMODE, int RELU, int NT>
__global__ __launch_bounds__(512, 2) void gemm256(
    const u16* __restrict__ A, const u16* __restrict__ B,
    const float* __restrict__ bias, void* __restrict__ Cp,
    int M, int N, int K, float alpha, int mtiles)
{
    __shared__ u16 smem[81920];   // 160 KiB

    const int nwg = gridDim.x;
    const int bid = blockIdx.x;
    const int cpx = nwg >> 3;
    const int swz = (bid & 7) * cpx + (bid >> 3);
    const int im = swz % mtiles, in = swz / mtiles;
    const int row0 = im * 256, col0 = in * 256;

    const int t = threadIdx.x;
    const int lane = t & 63;
    const int wid = t >> 6;
    const int wm = (wid >> 1) * 64;
    const int wn = (wid & 1) * 128;
    const int fr = lane & 15;
    const int g4 = lane >> 4;

    f32x4 acc[4][8];
#pragma unroll
    for (int m = 0; m < 4; ++m)
#pragma unroll
        for (int n = 0; n < 8; ++n) acc[m][n] = f32x4{0.f, 0.f, 0.f, 0.f};

    const int nt = K >> 6;
    const int srow = t >> 3;
    const int sc8  = t & 7;

    auto stage_half = [&](const u16* __restrict__ g, int rowbase, int h, u16* dst) {
#pragma unroll
        for (int j = 0; j < 2; ++j) {
            const int rl = h * 128 + srow + j * 64;
            const int c8 = sc8 ^ (rl & 7);
            const u16* sp = g + (long)(rowbase + rl) * K + c8 * 8;
            __builtin_amdgcn_global_load_lds((gptr1_t)sp,
                (lptr3_t)(dst + rl * 64 + sc8 * 8), 16, 0, 0);
        }
    };

    auto rdA = [&](const u16* base, int kk, int m) -> short8v {
        const int r = wm + m * 16 + fr;
        const int c8 = kk * 4 + g4;
        return *(const short8v*)(base + r * 64 + ((c8 ^ (r & 7)) << 3));
    };
    auto rdB = [&](const u16* base, int kk, int n) -> short8v {
        const int r = wn + n * 16 + fr;
        const int c8 = kk * 4 + g4;
        return *(const short8v*)(base + r * 64 + ((c8 ^ (r & 7)) << 3));
    };

    stage_half(A, row0, 0, smem);
    stage_half(A, row0, 1, smem);
    stage_half(B, col0, 0, smem + 32768);
    stage_half(B, col0, 1, smem + 32768);
    if (nt > 1) {
        stage_half(B + 64, col0, 0, smem + 49152);
        stage_half(B + 64, col0, 1, smem + 49152);
        WAITVM(4);
    } else {
        WAITVM(0);
    }
    barrier_fenced();

    short8v fa[4][2], fbl[4][2], fbh[4][2];

    for (int tt = 0; tt < nt; ++tt) {
        u16* rA = smem + ((tt & 1) << 14);
        u16* rB = smem + 32768 + ((unsigned)tt % 3u) * 16384;
        u16* sA = smem + ((~tt & 1) << 14);
        u16* sB = smem + 32768 + ((unsigned)(tt + 2) % 3u) * 16384;
        const bool stA = (tt + 1 < nt);
        const bool stB = (tt + 2 < nt);

        // phase 0
#pragma unroll
        for (int m = 0; m < 4; ++m) fa[m][0] = rdA(rA, 0, m);
#pragma unroll
        for (int n = 0; n < 4; ++n) fbl[n][0] = rdB(rB, 0, n);
        if (stA) stage_half(A + (tt + 1) * 64, row0, 0, sA);
        barrier_fenced();
        asm volatile("s_waitcnt lgkmcnt(0)" ::: "memory");
        __builtin_amdgcn_s_setprio(1);
#pragma unroll
        for (int m = 0; m < 4; ++m)
#pragma unroll
            for (int n = 0; n < 4; ++n)
                acc[m][n] = __builtin_amdgcn_mfma_f32_16x16x32_bf16(fa[m][0], fbl[n][0], acc[m][n], 0, 0, 0);
        __builtin_amdgcn_s_setprio(0);
        barrier_fenced();

        // phase 1
#pragma unroll
        for (int m = 0; m < 4; ++m) fa[m][1] = rdA(rA, 1, m);
#pragma unroll
        for (int n = 0; n < 4; ++n) fbl[n][1] = rdB(rB, 1, n);
        if (stA) stage_half(A + (tt + 1) * 64, row0, 1, sA);
        barrier_fenced();
        asm volatile("s_waitcnt lgkmcnt(0)" ::: "memory");
        __builtin_amdgcn_s_setprio(1);
#pragma unroll
        for (int m = 0; m < 4; ++m)
#pragma unroll
            for (int n = 0; n < 4; ++n)
                acc[m][n] = __builtin_amdgcn_mfma_f32_16x16x32_bf16(fa[m][1], fbl[n][1], acc[m][n], 0, 0, 0);
        __builtin_amdgcn_s_setprio(0);
        barrier_fenced();

        // phase 2
#pragma unroll
        for (int n = 0; n < 4; ++n) fbh[n][0] = rdB(rB, 0, n + 4);
        if (stB) stage_half(B + (tt + 2) * 64, col0, 0, sB);
        barrier_fenced();
        asm volatile("s_waitcnt lgkmcnt(0)" ::: "memory");
        __builtin_amdgcn_s_setprio(1);
#pragma unroll
        for (int m = 0; m < 4; ++m)
#pragma unroll
            for (int n = 0; n < 4; ++n)
                acc[m][n + 4] = __builtin_amdgcn_mfma_f32_16x16x32_bf16(fa[m][0], fbh[n][0], acc[m][n + 4], 0, 0, 0);
        __builtin_amdgcn_s_setprio(0);
        barrier_fenced();

        // phase 3
#pragma unroll
        for (int n = 0; n < 4; ++n) fbh[n][1] = rdB(rB, 1, n + 4);
        if (stB) stage_half(B + (tt + 2) * 64, col0, 1, sB);
        if (tt + 2 < nt) { WAITVM(4); } else { WAITVM(0); }
        barrier_fenced();
        asm volatile("s_waitcnt lgkmcnt(0)" ::: "memory");
        __builtin_amdgcn_s_setprio(1);
#pragma unroll
        for (int m = 0; m < 4; ++m)
#pragma unroll
            for (int n = 0; n < 4; ++n)
                acc[m][n + 4] = __builtin_amdgcn_mfma_f32_16x16x32_bf16(fa[m][1], fbh[n][1], acc[m][n + 4], 0, 0, 0);
        __builtin_amdgcn_s_setprio(0);
        barrier_fenced();
    }

    const int rq = (lane >> 4) * 4;
    float bv[8];
#pragma unroll
    for (int n = 0; n < 8; ++n)
        bv[n] = bias ? bias[col0 + wn + n * 16 + fr] : 0.f;
#pragma unroll
    for (int m = 0; m < 4; ++m) {
#pragma unroll
        for (int n = 0; n < 8; ++n) {
            const int col = col0 + wn + n * 16 + fr;
#pragma unroll
            for (int r = 0; r < 4; ++r) {
                const int row = row0 + wm + m * 16 + rq + r;
                float v = alpha * acc[m][n][r] + bv[n];
                if (RELU) v = fmaxf(v, 0.f);
                if (OUTMODE == 0) {
                    float* p = &((float*)Cp)[(long)row * N + col];
                    if (NT) __builtin_nontemporal_store(v, p);
                    else *p = v;
                } else {
                    ((u16*)Cp)[(long)row * N + col] = f2bf(v);
                }
            }
        }
    }
}

// ---------------------------------------------------------------------------
// V transpose: vt[bh, d, k] = qkv[b, k, 2D + h*64 + d]  (bf16)
// ---------------------------------------------------------------------------
__global__ void transpose_v(const u16* __restrict__ qkv, u16* __restrict__ vt) {
    const int kt = blockIdx.x * 64;
    const int bh = blockIdx.y;
    const int b = bh >> 4, h = bh & 15;
    const int t = threadIdx.x;
    __shared__ u16 tile[64][72];
    const long src = (long)b * Sq * (3 * Dm) + 2 * Dm + h * HDm;
#pragma unroll
    for (int i = 0; i < 2; ++i) {
        const int kl = i * 32 + (t >> 3);
        const int d0 = (t & 7) * 8;
        short8v v = *(const short8v*)(qkv + src + (long)(kt + kl) * (3 * Dm) + d0);
        *(short8v*)(&tile[kl][d0]) = v;
    }
    __syncthreads();
#pragma unroll
    for (int i = 0; i < 2; ++i) {
        const int d = i * 32 + (t >> 3);
        const int kk0 = (t & 7) * 8;
        short8v o;
#pragma unroll
        for (int j = 0; j < 8; ++j) o[j] = (short)tile[kk0 + j][d];
        *(short8v*)(vt + ((long)bh * HDm + d) * Sq + kt + kk0) = o;
    }
}

// ===========================================================================
// Fused flash attention (non-causal), D=64, S=2048.
// Grid (Sq/128, B*H), 256 threads = 4 waves; wave owns 32 q-rows (qn=0,1).
// Swapped QK^T: S^T = mfma(K, Q) -> lane holds S[kv=(lane>>4)*4+r+16*kvm]
// [q=16*qn+(lane&15)] -> row softmax = 15 local fmax + shfl_xor(16,32).
// Online softmax in exp2 domain (scale 0.125 folded into log2e factor).
// P^T->P via per-wave swizzled LDS buffer (wave-local, no barrier).
// PV: O^T = mfma(V^T, P) with V^T tiles from the pre-transposed VT16.
// K/V 64x64 tiles double-buffered via global_load_lds, XOR-swizzled.
// LDS = 2*8K (K) + 2*8K (V) + 4*4K (P) = 48 KiB -> 3 blocks/CU.
// ===========================================================================
__global__ __launch_bounds__(256) void flash_attn(
    const u16* __restrict__ qkv, const u16* __restrict__ vt,
    u16* __restrict__ ctx)
{
    __shared__ u16 Kt[2][64 * 64];
    __shared__ u16 Vt[2][64 * 64];
    __shared__ u16 Pt[4][32 * 64];

    const int bh = blockIdx.y;
    const int b = bh >> 4, h = bh & 15;
    const int t = threadIdx.x;
    const int lane = t & 63;
    const int wid = t >> 6;
    const int fr = lane & 15;
    const int g = lane >> 4;
    const int qb = blockIdx.x * 128 + wid * 32;

    // Q fragments (held in registers for the whole kernel)
    short8v aq[2][2];
#pragma unroll
    for (int qn = 0; qn < 2; ++qn)
#pragma unroll
        for (int kk = 0; kk < 2; ++kk) {
            const long q = (long)b * Sq + qb + qn * 16 + fr;
            aq[qn][kk] = *(const short8v*)(qkv + q * (3 * Dm) + h * 64 + kk * 32 + g * 8);
        }

    const int srl = t >> 3;              // 0..31 staging row
    const int sc8 = t & 7;               // 16B column
    const long kbase = (long)b * Sq * (3 * Dm) + Dm + h * 64;
    const long vbase = (long)bh * HDm * Sq;

    auto stage = [&](int kt, int buf) {
#pragma unroll
        for (int j = 0; j < 2; ++j) {
            const int rl = srl + j * 32;
            const int c8 = sc8 ^ (rl & 7);
            const u16* ks = qkv + kbase + (long)(kt * 64 + rl) * (3 * Dm) + c8 * 8;
            __builtin_amdgcn_global_load_lds((gptr1_t)ks,
                (lptr3_t)(&Kt[buf][rl * 64 + sc8 * 8]), 16, 0, 0);
            const u16* vs = vt + vbase + (long)rl * Sq + kt * 64 + c8 * 8;
            __builtin_amdgcn_global_load_lds((gptr1_t)vs,
                (lptr3_t)(&Vt[buf][rl * 64 + sc8 * 8]), 16, 0, 0);
        }
    };

    f32x4 accO[4][2];
#pragma unroll
    for (int dm = 0; dm < 4; ++dm)
#pragma unroll
        for (int qn = 0; qn < 2; ++qn) accO[dm][qn] = f32x4{0.f, 0.f, 0.f, 0.f};
    float m0 = -3.0e38f, m1 = -3.0e38f, l0 = 0.f, l1 = 0.f;
    const float cl2 = 0.125f * 1.44269504f;   // 1/sqrt(64) * log2(e)

    stage(0, 0);
    WAITVM(0);
    barrier_fenced();

    for (int kt = 0; kt < Sq / 64; ++kt) {
        const int cur = kt & 1;
        if (kt + 1 < Sq / 64) stage(kt + 1, cur ^ 1);

        // ---- S^T = K·Q^T : s[kvm][qn], value at [kv=16kvm+4g+r][q=16qn+fr] ----
        f32x4 s[4][2];
#pragma unroll
        for (int kvm = 0; kvm < 4; ++kvm)
#pragma unroll
            for (int qn = 0; qn < 2; ++qn) s[kvm][qn] = f32x4{0.f, 0.f, 0.f, 0.f};
        __builtin_amdgcn_s_setprio(1);
#pragma unroll
        for (int kvm = 0; kvm < 4; ++kvm)
#pragma unroll
            for (int kk = 0; kk < 2; ++kk) {
                const int r = kvm * 16 + fr;
                short8v bk = *(const short8v*)(&Kt[cur][r * 64 + (((kk * 4 + g) ^ (r & 7)) << 3)]);
#pragma unroll
                for (int qn = 0; qn < 2; ++qn)
                    s[kvm][qn] = __builtin_amdgcn_mfma_f32_16x16x32_bf16(bk, aq[qn][kk], s[kvm][qn], 0, 0, 0);
            }
        __builtin_amdgcn_s_setprio(0);

        // ---- online softmax (exp2 domain) ----
        float t0 = -3.0e38f, t1 = -3.0e38f;
#pragma unroll
        for (int kvm = 0; kvm < 4; ++kvm)
#pragma unroll
            for (int r = 0; r < 4; ++r) {
                t0 = fmaxf(t0, s[kvm][0][r]);
                t1 = fmaxf(t1, s[kvm][1][r]);
            }
        t0 = fmaxf(t0, __shfl_xor(t0, 16)); t0 = fmaxf(t0, __shfl_xor(t0, 32));
        t1 = fmaxf(t1, __shfl_xor(t1, 16)); t1 = fmaxf(t1, __shfl_xor(t1, 32));
        const float mn0 = fmaxf(m0, t0 * cl2);
        const float mn1 = fmaxf(m1, t1 * cl2);
        const float a0 = __builtin_amdgcn_exp2f(m0 - mn0);
        const float a1 = __builtin_amdgcn_exp2f(m1 - mn1);
        m0 = mn0; m1 = mn1;

        float ps0 = 0.f, ps1 = 0.f;
#pragma unroll
        for (int kvm = 0; kvm < 4; ++kvm)
#pragma unroll
            for (int r = 0; r < 4; ++r) {
                float p0 = __builtin_amdgcn_exp2f(s[kvm][0][r] * cl2 - mn0);
                float p1 = __builtin_amdgcn_exp2f(s[kvm][1][r] * cl2 - mn1);
                s[kvm][0][r] = p0; ps0 += p0;
                s[kvm][1][r] = p1; ps1 += p1;
            }
        ps0 += __shfl_xor(ps0, 16); ps0 += __shfl_xor(ps0, 32);
        ps1 += __shfl_xor(ps1, 16); ps1 += __shfl_xor(ps1, 32);
        l0 = l0 * a0 + ps0;
        l1 = l1 * a1 + ps1;
#pragma unroll
        for (int dm = 0; dm < 4; ++dm)
#pragma unroll
            for (int r = 0; r < 4; ++r) {
                accO[dm][0][r] *= a0;
                accO[dm][1][r] *= a1;
            }

        // ---- P^T -> P through per-wave swizzled LDS (wave-local) ----
#pragma unroll
        for (int kvm = 0; kvm < 4; ++kvm)
#pragma unroll
            for (int qn = 0; qn < 2; ++qn) {
                U16x4 hh = { f2bf(s[kvm][qn][0]), f2bf(s[kvm][qn][1]),
                             f2bf(s[kvm][qn][2]), f2bf(s[kvm][qn][3]) };
                const int q = qn * 16 + fr;
                const int off = q * 64 + (((2 * kvm + (g >> 1)) ^ (fr & 7)) << 3) + (g & 1) * 4;
                *(U16x4*)(&Pt[wid][off]) = hh;
            }
        short8v pb[2][2];
        short8v va[4][2];
#pragma unroll
        for (int qn = 0; qn < 2; ++qn)
#pragma unroll
            for (int ks = 0; ks < 2; ++ks) {
                const int q = qn * 16 + fr;
                pb[qn][ks] = *(const short8v*)(&Pt[wid][q * 64 + (((ks * 4 + g) ^ (fr & 7)) << 3)]);
            }
#pragma unroll
        for (int dm = 0; dm < 4; ++dm)
#pragma unroll
            for (int ks = 0; ks < 2; ++ks) {
                const int r = dm * 16 + fr;
                va[dm][ks] = *(const short8v*)(&Vt[cur][r * 64 + (((ks * 4 + g) ^ (r & 7)) << 3)]);
            }

        // ---- O^T += V^T · P^T ----
        __builtin_amdgcn_s_setprio(1);
#pragma unroll
        for (int dm = 0; dm < 4; ++dm)
#pragma unroll
            for (int qn = 0; qn < 2; ++qn)
#pragma unroll
                for (int ks = 0; ks < 2; ++ks)
                    accO[dm][qn] = __builtin_amdgcn_mfma_f32_16x16x32_bf16(va[dm][ks], pb[qn][ks], accO[dm][qn], 0, 0, 0);
        __builtin_amdgcn_s_setprio(0);

        WAITVM(0);
        barrier_fenced();
    }

    // ---- write O = accO / l : lane covers q=16qn+fr, d=16dm+4g+r ----
    const float inv0 = 1.f / l0;
    const float inv1 = 1.f / l1;
#pragma unroll
    for (int dm = 0; dm < 4; ++dm)
#pragma unroll
        for (int qn = 0; qn < 2; ++qn) {
            const float inv = qn ? inv1 : inv0;
            U16x4 hh = { f2bf(accO[dm][qn][0] * inv), f2bf(accO[dm][qn][1] * inv),
                         f2bf(accO[dm][qn][2] * inv), f2bf(accO[dm][qn][3] * inv) };
            const long q = (long)b * Sq + qb + qn * 16 + fr;
            *(U16x4*)(ctx + q * Dm + h * 64 + dm * 16 + g * 4) = hh;
        }
}

// ---------------------------------------------------------------------------
// residual + LayerNorm.
// ---------------------------------------------------------------------------
template <int W32>
__global__ void ln_kernel(float* __restrict__ x, const float* __restrict__ res,
                          const float* __restrict__ g, const float* __restrict__ be,
                          u16* __restrict__ out16) {
    const int row = blockIdx.x;
    const int t = threadIdx.x;
    const long base = (long)row * Dm + t * 4;
    float4 a = *(const float4*)(x + base);
    float4 b = *(const float4*)(res + base);
    float v0 = a.x + b.x, v1 = a.y + b.y, v2 = a.z + b.z, v3 = a.w + b.w;
    float s = v0 + v1 + v2 + v3;
    float q = v0 * v0 + v1 * v1 + v2 * v2 + v3 * v3;

    const int wave = t >> 6, lane = t & 63;
    __shared__ float rs[4], rq2[4];
#pragma unroll
    for (int o = 32; o; o >>= 1) { s += __shfl_xor(s, o); q += __shfl_xor(q, o); }
    if (lane == 0) { rs[wave] = s; rq2[wave] = q; }
    __syncthreads();
    s = rs[0] + rs[1] + rs[2] + rs[3];
    q = rq2[0] + rq2[1] + rq2[2] + rq2[3];

    const float mean = s * (1.f / Dm);
    const float var = q * (1.f / Dm) - mean * mean;
    const float rstd = rsqrtf(var + 1e-5f);
    const float4 gg = *(const float4*)(g + t * 4);
    const float4 bb = *(const float4*)(be + t * 4);
    float o0 = (v0 - mean) * rstd * gg.x + bb.x;
    float o1 = (v1 - mean) * rstd * gg.y + bb.y;
    float o2 = (v2 - mean) * rstd * gg.z + bb.z;
    float o3 = (v3 - mean) * rstd * gg.w + bb.w;
    U16x4 h = { f2bf(o0), f2bf(o1), f2bf(o2), f2bf(o3) };
    *(U16x4*)(out16 + base) = h;
    if (W32) {
        float4 ov = { o0, o1, o2, o3 };
        *(float4*)(x + base) = ov;
    }
}

// ---------------------------------------------------------------------------
extern "C" void kernel_launch(void* const* d_in, const int* in_sizes, int n_in,
                              void* d_out, int out_size, void* d_ws, size_t ws_size,
                              hipStream_t stream) {
    const int*   tokens = (const int*)  d_in[0];
    const float* emb    = (const float*)d_in[1];
    const float* pos    = (const float*)d_in[2];
    const float* w_qkv  = (const float*)d_in[3];
    const float* b_qkv  = (const float*)d_in[4];
    const float* w_o    = (const float*)d_in[5];
    const float* b_o    = (const float*)d_in[6];
    const float* g1     = (const float*)d_in[7];
    const float* beta1  = (const float*)d_in[8];
    const float* w1     = (const float*)d_in[9];
    const float* b1     = (const float*)d_in[10];
    const float* w2     = (const float*)d_in[11];
    const float* b2     = (const float*)d_in[12];
    const float* g2     = (const float*)d_in[13];
    const float* beta2  = (const float*)d_in[14];
    const float* w_fc   = (const float*)d_in[15];
    const float* b_fc   = (const float*)d_in[16];

    char* ws = (char*)d_ws;
    size_t off = 0;
    auto alloc = [&](size_t bytes) { void* p = ws + off; off += (bytes + 255) & ~(size_t)255; return p; };

    float* X32   = (float*)alloc((size_t)MTOK * Dm * 4);
    u16*   XB16  = (u16*)  alloc((size_t)MTOK * Dm * 2);
    u16*   QKV16 = (u16*)  alloc((size_t)MTOK * 3 * Dm * 2);
    u16*   VT16  = (u16*)  alloc((size_t)64 * HDm * Sq * 2);
    u16*   CTX16 = (u16*)  alloc((size_t)MTOK * Dm * 2);
    float* ATT32 = (float*)alloc((size_t)MTOK * Dm * 4);
    u16*   H16   = (u16*)  alloc((size_t)MTOK * DFFm * 2);
    u16*   WQ16  = (u16*)  alloc((size_t)3 * Dm * Dm * 2);
    u16*   WO16  = (u16*)  alloc((size_t)Dm * Dm * 2);
    u16*   W116  = (u16*)  alloc((size_t)DFFm * Dm * 2);
    u16*   W216  = (u16*)  alloc((size_t)Dm * DFFm * 2);
    u16*   WFC16 = (u16*)  alloc((size_t)Vv * Dm * 2);

    const dim3 blk(256);
    const dim3 blk512(512);

    // --- weight conversions ---
    to_bf16<<<1024, blk, 0, stream>>>(w_qkv, WQ16, (long)3 * Dm * Dm / 4);
    to_bf16<<<1024, blk, 0, stream>>>(w_o,   WO16, (long)Dm * Dm / 4);
    to_bf16<<<1024, blk, 0, stream>>>(w1,    W116, (long)DFFm * Dm / 4);
    to_bf16<<<1024, blk, 0, stream>>>(w2,    W216, (long)Dm * DFFm / 4);
    to_bf16<<<2048, blk, 0, stream>>>(w_fc,  WFC16, (long)Vv * Dm / 4);

    // --- embedding ---
    embed_kernel<<<MTOK, blk, 0, stream>>>(tokens, emb, pos, X32, XB16);

    // --- QKV projection: [8192,3072], K=1024 (384 blocks) ---
    gemm256<1, 0, 0><<<dim3((MTOK / 256) * ((3 * Dm) / 256)), blk512, 0, stream>>>(
        XB16, WQ16, b_qkv, QKV16, MTOK, 3 * Dm, Dm, 1.f, MTOK / 256);

    // --- V transpose ---
    transpose_v<<<dim3(Sq / 64, Bz * Hh), blk, 0, stream>>>(QKV16, VT16);

    // --- fused flash attention -> CTX16 ---
    flash_attn<<<dim3(Sq / 128, Bz * Hh), blk, 0, stream>>>(QKV16, VT16, CTX16);

    // --- attn_out = ctx @ w_o^T + b_o (fp32), [8192,1024] K=1024 ---
    gemm256<0, 0, 0><<<dim3((MTOK / 256) * (Dm / 256)), blk512, 0, stream>>>(
        CTX16, WO16, b_o, ATT32, MTOK, Dm, Dm, 1.f, MTOK / 256);

    // --- LN1 ---
    ln_kernel<1><<<MTOK, blk, 0, stream>>>(X32, ATT32, g1, beta1, XB16);

    // --- FFN1: h = relu(x1 @ w1^T + b1), [8192,4096] K=1024 ---
    gemm256<1, 1, 0><<<dim3((MTOK / 256) * (DFFm / 256)), blk512, 0, stream>>>(
        XB16, W116, b1, H16, MTOK, DFFm, Dm, 1.f, MTOK / 256);

    // --- FFN2: ffn = h @ w2^T + b2 (fp32), [8192,1024] K=4096 ---
    gemm256<0, 0, 0><<<dim3((MTOK / 256) * (Dm / 256)), blk512, 0, stream>>>(
        H16, W216, b2, ATT32, MTOK, Dm, DFFm, 1.f, MTOK / 256);

    // --- LN2 ---
    ln_kernel<0><<<MTOK, blk, 0, stream>>>(X32, ATT32, g2, beta2, XB16);

    // --- final vocab projection: [8192,32000] K=1024, NT stores (4000 blocks) ---
    gemm256<0, 0, 1><<<dim3((MTOK / 256) * (Vv / 256)), blk512, 0, stream>>>(
        XB16, WFC16, b_fc, (float*)d_out, MTOK, Vv, Dm, 1.f, MTOK / 256);
}

// Round 5
// 1153.900 us; speedup vs baseline: 1.9579x; 1.1240x over previous
//
#include <hip/hip_runtime.h>
#include <stdint.h>

#define Bz   4
#define Sq   2048
#define Dm   1024
#define Hh   16
#define HDm  64
#define DFFm 4096
#define Vv   32000
#define MTOK (Bz * Sq)   // 8192

typedef unsigned short u16;
typedef __attribute__((ext_vector_type(8))) short short8v;   // 8 bf16 = 4 VGPR (MFMA frag)
typedef __attribute__((ext_vector_type(4))) float f32x4;

struct alignas(8) U16x4 { u16 x, y, z, w; };

typedef const __attribute__((address_space(1))) void* gptr1_t;
typedef __attribute__((address_space(3))) void* lptr3_t;

__device__ __forceinline__ u16 f2bf(float f) {
    union { float f; unsigned u; } v; v.f = f;
    unsigned r = v.u + 0x7FFF + ((v.u >> 16) & 1);   // RNE
    return (u16)(r >> 16);
}
__device__ __forceinline__ float bf2f(u16 h) {
    union { unsigned u; float f; } v; v.u = ((unsigned)h) << 16;
    return v.f;
}

#define WAITVM(N) asm volatile("s_waitcnt vmcnt(" #N ")" ::: "memory")

__device__ __forceinline__ void barrier_fenced() {
    asm volatile("" ::: "memory");
    __builtin_amdgcn_s_barrier();
    asm volatile("" ::: "memory");
}

// ---------------------------------------------------------------------------
// fp32 -> bf16 conversion (vectorized, grid-stride)
// ---------------------------------------------------------------------------
__global__ void to_bf16(const float* __restrict__ in, u16* __restrict__ out, long n4) {
    long i = (long)blockIdx.x * blockDim.x + threadIdx.x;
    const long stride = (long)gridDim.x * blockDim.x;
    for (; i < n4; i += stride) {
        float4 v = *(const float4*)(in + i * 4);
        U16x4 h = { f2bf(v.x), f2bf(v.y), f2bf(v.z), f2bf(v.w) };
        *(U16x4*)(out + i * 4) = h;
    }
}

// ---------------------------------------------------------------------------
// embedding + positional: x = emb[tok] + pos ; writes fp32 and bf16 copies
// ---------------------------------------------------------------------------
__global__ void embed_kernel(const int* __restrict__ tok, const float* __restrict__ emb,
                             const float* __restrict__ pos, float* __restrict__ x32,
                             u16* __restrict__ x16) {
    const int row = blockIdx.x;            // b*S + s
    const int s = row & (Sq - 1);
    const int t = threadIdx.x;             // 256 threads * 4 floats = 1024
    const long tokid = tok[row];
    float4 e = *(const float4*)(emb + tokid * Dm + t * 4);
    float4 p = *(const float4*)(pos + (long)s * Dm + t * 4);
    float4 v = { e.x + p.x, e.y + p.y, e.z + p.z, e.w + p.w };
    const long base = (long)row * Dm + t * 4;
    *(float4*)(x32 + base) = v;
    U16x4 h = { f2bf(v.x), f2bf(v.y), f2bf(v.z), f2bf(v.w) };
    *(U16x4*)(x16 + base) = h;
}

// ===========================================================================
// 256x256 8-barrier/K-tile GEMM (r3 structure; row-outer tile order).
// C[M,N] = alpha*A[M,K]*B[N,K]^T + bias.  M%256==0, N%256==0, K%64==0,
// nt=K/64 >= 3, grid %8 == 0.  512 threads = 8 waves as 4M x 2N.
// LDS 160 KiB: A dbuf (2x32KB) + B tribuf (3x32KB); A dist-1, B dist-2
// prefetch; single vmcnt(4) per K-tile before the p3 closing barrier.
// Tile order: im = swz/ntn (slow), in = swz%ntn (fast). Each XCD pins one
// 0.5 MB A-panel in its private L2 for a whole B-sweep; all XCDs sweep B
// in phase so each B panel is fetched into L3 once. (r4 column-outer order
// re-fetched ~1 GB of A/B on the FC GEMM.)
// ===========================================================================
template <int OUTMODE, int RELU>
__global__ __launch_bounds__(512, 2) void gemm256(
    const u16* __restrict__ A, const u16* __restrict__ B,
    const float* __restrict__ bias, void* __restrict__ Cp,
    int M, int N, int K, float alpha, int ntn)
{
    __shared__ u16 smem[81920];   // 160 KiB

    const int nwg = gridDim.x;
    const int bid = blockIdx.x;
    const int cpx = nwg >> 3;
    const int swz = (bid & 7) * cpx + (bid >> 3);
    const int im = swz / ntn, in = swz % ntn;
    const int row0 = im * 256, col0 = in * 256;

    const int t = threadIdx.x;
    const int lane = t & 63;
    const int wid = t >> 6;
    const int wm = (wid >> 1) * 64;
    const int wn = (wid & 1) * 128;
    const int fr = lane & 15;
    const int g4 = lane >> 4;

    f32x4 acc[4][8];
#pragma unroll
    for (int m = 0; m < 4; ++m)
#pragma unroll
        for (int n = 0; n < 8; ++n) acc[m][n] = f32x4{0.f, 0.f, 0.f, 0.f};

    const int nt = K >> 6;
    const int srow = t >> 3;
    const int sc8  = t & 7;

    auto stage_half = [&](const u16* __restrict__ g, int rowbase, int h, u16* dst) {
#pragma unroll
        for (int j = 0; j < 2; ++j) {
            const int rl = h * 128 + srow + j * 64;
            const int c8 = sc8 ^ (rl & 7);
            const u16* sp = g + (long)(rowbase + rl) * K + c8 * 8;
            __builtin_amdgcn_global_load_lds((gptr1_t)sp,
                (lptr3_t)(dst + rl * 64 + sc8 * 8), 16, 0, 0);
        }
    };

    auto rdA = [&](const u16* base, int kk, int m) -> short8v {
        const int r = wm + m * 16 + fr;
        const int c8 = kk * 4 + g4;
        return *(const short8v*)(base + r * 64 + ((c8 ^ (r & 7)) << 3));
    };
    auto rdB = [&](const u16* base, int kk, int n) -> short8v {
        const int r = wn + n * 16 + fr;
        const int c8 = kk * 4 + g4;
        return *(const short8v*)(base + r * 64 + ((c8 ^ (r & 7)) << 3));
    };

    stage_half(A, row0, 0, smem);
    stage_half(A, row0, 1, smem);
    stage_half(B, col0, 0, smem + 32768);
    stage_half(B, col0, 1, smem + 32768);
    if (nt > 1) {
        stage_half(B + 64, col0, 0, smem + 49152);
        stage_half(B + 64, col0, 1, smem + 49152);
        WAITVM(4);
    } else {
        WAITVM(0);
    }
    barrier_fenced();

    short8v fa[4][2], fbl[4][2], fbh[4][2];

    for (int tt = 0; tt < nt; ++tt) {
        u16* rA = smem + ((tt & 1) << 14);
        u16* rB = smem + 32768 + ((unsigned)tt % 3u) * 16384;
        u16* sA = smem + ((~tt & 1) << 14);
        u16* sB = smem + 32768 + ((unsigned)(tt + 2) % 3u) * 16384;
        const bool stA = (tt + 1 < nt);
        const bool stB = (tt + 2 < nt);

        // phase 0
#pragma unroll
        for (int m = 0; m < 4; ++m) fa[m][0] = rdA(rA, 0, m);
#pragma unroll
        for (int n = 0; n < 4; ++n) fbl[n][0] = rdB(rB, 0, n);
        if (stA) stage_half(A + (tt + 1) * 64, row0, 0, sA);
        barrier_fenced();
        asm volatile("s_waitcnt lgkmcnt(0)" ::: "memory");
        __builtin_amdgcn_s_setprio(1);
#pragma unroll
        for (int m = 0; m < 4; ++m)
#pragma unroll
            for (int n = 0; n < 4; ++n)
                acc[m][n] = __builtin_amdgcn_mfma_f32_16x16x32_bf16(fa[m][0], fbl[n][0], acc[m][n], 0, 0, 0);
        __builtin_amdgcn_s_setprio(0);
        barrier_fenced();

        // phase 1
#pragma unroll
        for (int m = 0; m < 4; ++m) fa[m][1] = rdA(rA, 1, m);
#pragma unroll
        for (int n = 0; n < 4; ++n) fbl[n][1] = rdB(rB, 1, n);
        if (stA) stage_half(A + (tt + 1) * 64, row0, 1, sA);
        barrier_fenced();
        asm volatile("s_waitcnt lgkmcnt(0)" ::: "memory");
        __builtin_amdgcn_s_setprio(1);
#pragma unroll
        for (int m = 0; m < 4; ++m)
#pragma unroll
            for (int n = 0; n < 4; ++n)
                acc[m][n] = __builtin_amdgcn_mfma_f32_16x16x32_bf16(fa[m][1], fbl[n][1], acc[m][n], 0, 0, 0);
        __builtin_amdgcn_s_setprio(0);
        barrier_fenced();

        // phase 2
#pragma unroll
        for (int n = 0; n < 4; ++n) fbh[n][0] = rdB(rB, 0, n + 4);
        if (stB) stage_half(B + (tt + 2) * 64, col0, 0, sB);
        barrier_fenced();
        asm volatile("s_waitcnt lgkmcnt(0)" ::: "memory");
        __builtin_amdgcn_s_setprio(1);
#pragma unroll
        for (int m = 0; m < 4; ++m)
#pragma unroll
            for (int n = 0; n < 4; ++n)
                acc[m][n + 4] = __builtin_amdgcn_mfma_f32_16x16x32_bf16(fa[m][0], fbh[n][0], acc[m][n + 4], 0, 0, 0);
        __builtin_amdgcn_s_setprio(0);
        barrier_fenced();

        // phase 3
#pragma unroll
        for (int n = 0; n < 4; ++n) fbh[n][1] = rdB(rB, 1, n + 4);
        if (stB) stage_half(B + (tt + 2) * 64, col0, 1, sB);
        if (tt + 2 < nt) { WAITVM(4); } else { WAITVM(0); }
        barrier_fenced();
        asm volatile("s_waitcnt lgkmcnt(0)" ::: "memory");
        __builtin_amdgcn_s_setprio(1);
#pragma unroll
        for (int m = 0; m < 4; ++m)
#pragma unroll
            for (int n = 0; n < 4; ++n)
                acc[m][n + 4] = __builtin_amdgcn_mfma_f32_16x16x32_bf16(fa[m][1], fbh[n][1], acc[m][n + 4], 0, 0, 0);
        __builtin_amdgcn_s_setprio(0);
        barrier_fenced();
    }

    const int rq = (lane >> 4) * 4;
    float bv[8];
#pragma unroll
    for (int n = 0; n < 8; ++n)
        bv[n] = bias ? bias[col0 + wn + n * 16 + fr] : 0.f;
#pragma unroll
    for (int m = 0; m < 4; ++m) {
#pragma unroll
        for (int n = 0; n < 8; ++n) {
            const int col = col0 + wn + n * 16 + fr;
#pragma unroll
            for (int r = 0; r < 4; ++r) {
                const int row = row0 + wm + m * 16 + rq + r;
                float v = alpha * acc[m][n][r] + bv[n];
                if (RELU) v = fmaxf(v, 0.f);
                if (OUTMODE == 0)
                    ((float*)Cp)[(long)row * N + col] = v;
                else
                    ((u16*)Cp)[(long)row * N + col] = f2bf(v);
            }
        }
    }
}

// ---------------------------------------------------------------------------
// V transpose: vt[bh, d, k] = qkv[b, k, 2D + h*64 + d]  (bf16)
// ---------------------------------------------------------------------------
__global__ void transpose_v(const u16* __restrict__ qkv, u16* __restrict__ vt) {
    const int kt = blockIdx.x * 64;
    const int bh = blockIdx.y;
    const int b = bh >> 4, h = bh & 15;
    const int t = threadIdx.x;
    __shared__ u16 tile[64][72];
    const long src = (long)b * Sq * (3 * Dm) + 2 * Dm + h * HDm;
#pragma unroll
    for (int i = 0; i < 2; ++i) {
        const int kl = i * 32 + (t >> 3);
        const int d0 = (t & 7) * 8;
        short8v v = *(const short8v*)(qkv + src + (long)(kt + kl) * (3 * Dm) + d0);
        *(short8v*)(&tile[kl][d0]) = v;
    }
    __syncthreads();
#pragma unroll
    for (int i = 0; i < 2; ++i) {
        const int d = i * 32 + (t >> 3);
        const int kk0 = (t & 7) * 8;
        short8v o;
#pragma unroll
        for (int j = 0; j < 8; ++j) o[j] = (short)tile[kk0 + j][d];
        *(short8v*)(vt + ((long)bh * HDm + d) * Sq + kt + kk0) = o;
    }
}

// ===========================================================================
// Fused flash attention (non-causal), D=64, S=2048.  (unchanged from r4)
// ===========================================================================
__global__ __launch_bounds__(256) void flash_attn(
    const u16* __restrict__ qkv, const u16* __restrict__ vt,
    u16* __restrict__ ctx)
{
    __shared__ u16 Kt[2][64 * 64];
    __shared__ u16 Vt[2][64 * 64];
    __shared__ u16 Pt[4][32 * 64];

    const int bh = blockIdx.y;
    const int b = bh >> 4, h = bh & 15;
    const int t = threadIdx.x;
    const int lane = t & 63;
    const int wid = t >> 6;
    const int fr = lane & 15;
    const int g = lane >> 4;
    const int qb = blockIdx.x * 128 + wid * 32;

    short8v aq[2][2];
#pragma unroll
    for (int qn = 0; qn < 2; ++qn)
#pragma unroll
        for (int kk = 0; kk < 2; ++kk) {
            const long q = (long)b * Sq + qb + qn * 16 + fr;
            aq[qn][kk] = *(const short8v*)(qkv + q * (3 * Dm) + h * 64 + kk * 32 + g * 8);
        }

    const int srl = t >> 3;
    const int sc8 = t & 7;
    const long kbase = (long)b * Sq * (3 * Dm) + Dm + h * 64;
    const long vbase = (long)bh * HDm * Sq;

    auto stage = [&](int kt, int buf) {
#pragma unroll
        for (int j = 0; j < 2; ++j) {
            const int rl = srl + j * 32;
            const int c8 = sc8 ^ (rl & 7);
            const u16* ks = qkv + kbase + (long)(kt * 64 + rl) * (3 * Dm) + c8 * 8;
            __builtin_amdgcn_global_load_lds((gptr1_t)ks,
                (lptr3_t)(&Kt[buf][rl * 64 + sc8 * 8]), 16, 0, 0);
            const u16* vs = vt + vbase + (long)rl * Sq + kt * 64 + c8 * 8;
            __builtin_amdgcn_global_load_lds((gptr1_t)vs,
                (lptr3_t)(&Vt[buf][rl * 64 + sc8 * 8]), 16, 0, 0);
        }
    };

    f32x4 accO[4][2];
#pragma unroll
    for (int dm = 0; dm < 4; ++dm)
#pragma unroll
        for (int qn = 0; qn < 2; ++qn) accO[dm][qn] = f32x4{0.f, 0.f, 0.f, 0.f};
    float m0 = -3.0e38f, m1 = -3.0e38f, l0 = 0.f, l1 = 0.f;
    const float cl2 = 0.125f * 1.44269504f;

    stage(0, 0);
    WAITVM(0);
    barrier_fenced();

    for (int kt = 0; kt < Sq / 64; ++kt) {
        const int cur = kt & 1;
        if (kt + 1 < Sq / 64) stage(kt + 1, cur ^ 1);

        f32x4 s[4][2];
#pragma unroll
        for (int kvm = 0; kvm < 4; ++kvm)
#pragma unroll
            for (int qn = 0; qn < 2; ++qn) s[kvm][qn] = f32x4{0.f, 0.f, 0.f, 0.f};
        __builtin_amdgcn_s_setprio(1);
#pragma unroll
        for (int kvm = 0; kvm < 4; ++kvm)
#pragma unroll
            for (int kk = 0; kk < 2; ++kk) {
                const int r = kvm * 16 + fr;
                short8v bk = *(const short8v*)(&Kt[cur][r * 64 + (((kk * 4 + g) ^ (r & 7)) << 3)]);
#pragma unroll
                for (int qn = 0; qn < 2; ++qn)
                    s[kvm][qn] = __builtin_amdgcn_mfma_f32_16x16x32_bf16(bk, aq[qn][kk], s[kvm][qn], 0, 0, 0);
            }
        __builtin_amdgcn_s_setprio(0);

        float t0 = -3.0e38f, t1 = -3.0e38f;
#pragma unroll
        for (int kvm = 0; kvm < 4; ++kvm)
#pragma unroll
            for (int r = 0; r < 4; ++r) {
                t0 = fmaxf(t0, s[kvm][0][r]);
                t1 = fmaxf(t1, s[kvm][1][r]);
            }
        t0 = fmaxf(t0, __shfl_xor(t0, 16)); t0 = fmaxf(t0, __shfl_xor(t0, 32));
        t1 = fmaxf(t1, __shfl_xor(t1, 16)); t1 = fmaxf(t1, __shfl_xor(t1, 32));
        const float mn0 = fmaxf(m0, t0 * cl2);
        const float mn1 = fmaxf(m1, t1 * cl2);
        const float a0 = __builtin_amdgcn_exp2f(m0 - mn0);
        const float a1 = __builtin_amdgcn_exp2f(m1 - mn1);
        m0 = mn0; m1 = mn1;

        float ps0 = 0.f, ps1 = 0.f;
#pragma unroll
        for (int kvm = 0; kvm < 4; ++kvm)
#pragma unroll
            for (int r = 0; r < 4; ++r) {
                float p0 = __builtin_amdgcn_exp2f(s[kvm][0][r] * cl2 - mn0);
                float p1 = __builtin_amdgcn_exp2f(s[kvm][1][r] * cl2 - mn1);
                s[kvm][0][r] = p0; ps0 += p0;
                s[kvm][1][r] = p1; ps1 += p1;
            }
        ps0 += __shfl_xor(ps0, 16); ps0 += __shfl_xor(ps0, 32);
        ps1 += __shfl_xor(ps1, 16); ps1 += __shfl_xor(ps1, 32);
        l0 = l0 * a0 + ps0;
        l1 = l1 * a1 + ps1;
#pragma unroll
        for (int dm = 0; dm < 4; ++dm)
#pragma unroll
            for (int r = 0; r < 4; ++r) {
                accO[dm][0][r] *= a0;
                accO[dm][1][r] *= a1;
            }

#pragma unroll
        for (int kvm = 0; kvm < 4; ++kvm)
#pragma unroll
            for (int qn = 0; qn < 2; ++qn) {
                U16x4 hh = { f2bf(s[kvm][qn][0]), f2bf(s[kvm][qn][1]),
                             f2bf(s[kvm][qn][2]), f2bf(s[kvm][qn][3]) };
                const int q = qn * 16 + fr;
                const int off = q * 64 + (((2 * kvm + (g >> 1)) ^ (fr & 7)) << 3) + (g & 1) * 4;
                *(U16x4*)(&Pt[wid][off]) = hh;
            }
        short8v pb[2][2];
        short8v va[4][2];
#pragma unroll
        for (int qn = 0; qn < 2; ++qn)
#pragma unroll
            for (int ks = 0; ks < 2; ++ks) {
                const int q = qn * 16 + fr;
                pb[qn][ks] = *(const short8v*)(&Pt[wid][q * 64 + (((ks * 4 + g) ^ (fr & 7)) << 3)]);
            }
#pragma unroll
        for (int dm = 0; dm < 4; ++dm)
#pragma unroll
            for (int ks = 0; ks < 2; ++ks) {
                const int r = dm * 16 + fr;
                va[dm][ks] = *(const short8v*)(&Vt[cur][r * 64 + (((ks * 4 + g) ^ (r & 7)) << 3)]);
            }

        __builtin_amdgcn_s_setprio(1);
#pragma unroll
        for (int dm = 0; dm < 4; ++dm)
#pragma unroll
            for (int qn = 0; qn < 2; ++qn)
#pragma unroll
                for (int ks = 0; ks < 2; ++ks)
                    accO[dm][qn] = __builtin_amdgcn_mfma_f32_16x16x32_bf16(va[dm][ks], pb[qn][ks], accO[dm][qn], 0, 0, 0);
        __builtin_amdgcn_s_setprio(0);

        WAITVM(0);
        barrier_fenced();
    }

    const float inv0 = 1.f / l0;
    const float inv1 = 1.f / l1;
#pragma unroll
    for (int dm = 0; dm < 4; ++dm)
#pragma unroll
        for (int qn = 0; qn < 2; ++qn) {
            const float inv = qn ? inv1 : inv0;
            U16x4 hh = { f2bf(accO[dm][qn][0] * inv), f2bf(accO[dm][qn][1] * inv),
                         f2bf(accO[dm][qn][2] * inv), f2bf(accO[dm][qn][3] * inv) };
            const long q = (long)b * Sq + qb + qn * 16 + fr;
            *(U16x4*)(ctx + q * Dm + h * 64 + dm * 16 + g * 4) = hh;
        }
}

// ---------------------------------------------------------------------------
// residual + LayerNorm.
// ---------------------------------------------------------------------------
template <int W32>
__global__ void ln_kernel(float* __restrict__ x, const float* __restrict__ res,
                          const float* __restrict__ g, const float* __restrict__ be,
                          u16* __restrict__ out16) {
    const int row = blockIdx.x;
    const int t = threadIdx.x;
    const long base = (long)row * Dm + t * 4;
    float4 a = *(const float4*)(x + base);
    float4 b = *(const float4*)(res + base);
    float v0 = a.x + b.x, v1 = a.y + b.y, v2 = a.z + b.z, v3 = a.w + b.w;
    float s = v0 + v1 + v2 + v3;
    float q = v0 * v0 + v1 * v1 + v2 * v2 + v3 * v3;

    const int wave = t >> 6, lane = t & 63;
    __shared__ float rs[4], rq2[4];
#pragma unroll
    for (int o = 32; o; o >>= 1) { s += __shfl_xor(s, o); q += __shfl_xor(q, o); }
    if (lane == 0) { rs[wave] = s; rq2[wave] = q; }
    __syncthreads();
    s = rs[0] + rs[1] + rs[2] + rs[3];
    q = rq2[0] + rq2[1] + rq2[2] + rq2[3];

    const float mean = s * (1.f / Dm);
    const float var = q * (1.f / Dm) - mean * mean;
    const float rstd = rsqrtf(var + 1e-5f);
    const float4 gg = *(const float4*)(g + t * 4);
    const float4 bb = *(const float4*)(be + t * 4);
    float o0 = (v0 - mean) * rstd * gg.x + bb.x;
    float o1 = (v1 - mean) * rstd * gg.y + bb.y;
    float o2 = (v2 - mean) * rstd * gg.z + bb.z;
    float o3 = (v3 - mean) * rstd * gg.w + bb.w;
    U16x4 h = { f2bf(o0), f2bf(o1), f2bf(o2), f2bf(o3) };
    *(U16x4*)(out16 + base) = h;
    if (W32) {
        float4 ov = { o0, o1, o2, o3 };
        *(float4*)(x + base) = ov;
    }
}

// ---------------------------------------------------------------------------
extern "C" void kernel_launch(void* const* d_in, const int* in_sizes, int n_in,
                              void* d_out, int out_size, void* d_ws, size_t ws_size,
                              hipStream_t stream) {
    const int*   tokens = (const int*)  d_in[0];
    const float* emb    = (const float*)d_in[1];
    const float* pos    = (const float*)d_in[2];
    const float* w_qkv  = (const float*)d_in[3];
    const float* b_qkv  = (const float*)d_in[4];
    const float* w_o    = (const float*)d_in[5];
    const float* b_o    = (const float*)d_in[6];
    const float* g1     = (const float*)d_in[7];
    const float* beta1  = (const float*)d_in[8];
    const float* w1     = (const float*)d_in[9];
    const float* b1     = (const float*)d_in[10];
    const float* w2     = (const float*)d_in[11];
    const float* b2     = (const float*)d_in[12];
    const float* g2     = (const float*)d_in[13];
    const float* beta2  = (const float*)d_in[14];
    const float* w_fc   = (const float*)d_in[15];
    const float* b_fc   = (const float*)d_in[16];

    char* ws = (char*)d_ws;
    size_t off = 0;
    auto alloc = [&](size_t bytes) { void* p = ws + off; off += (bytes + 255) & ~(size_t)255; return p; };

    float* X32   = (float*)alloc((size_t)MTOK * Dm * 4);
    u16*   XB16  = (u16*)  alloc((size_t)MTOK * Dm * 2);
    u16*   QKV16 = (u16*)  alloc((size_t)MTOK * 3 * Dm * 2);
    u16*   VT16  = (u16*)  alloc((size_t)64 * HDm * Sq * 2);
    u16*   CTX16 = (u16*)  alloc((size_t)MTOK * Dm * 2);
    float* ATT32 = (float*)alloc((size_t)MTOK * Dm * 4);
    u16*   H16   = (u16*)  alloc((size_t)MTOK * DFFm * 2);
    u16*   WQ16  = (u16*)  alloc((size_t)3 * Dm * Dm * 2);
    u16*   WO16  = (u16*)  alloc((size_t)Dm * Dm * 2);
    u16*   W116  = (u16*)  alloc((size_t)DFFm * Dm * 2);
    u16*   W216  = (u16*)  alloc((size_t)Dm * DFFm * 2);
    u16*   WFC16 = (u16*)  alloc((size_t)Vv * Dm * 2);

    const dim3 blk(256);
    const dim3 blk512(512);

    // --- weight conversions ---
    to_bf16<<<1024, blk, 0, stream>>>(w_qkv, WQ16, (long)3 * Dm * Dm / 4);
    to_bf16<<<1024, blk, 0, stream>>>(w_o,   WO16, (long)Dm * Dm / 4);
    to_bf16<<<1024, blk, 0, stream>>>(w1,    W116, (long)DFFm * Dm / 4);
    to_bf16<<<1024, blk, 0, stream>>>(w2,    W216, (long)Dm * DFFm / 4);
    to_bf16<<<2048, blk, 0, stream>>>(w_fc,  WFC16, (long)Vv * Dm / 4);

    // --- embedding ---
    embed_kernel<<<MTOK, blk, 0, stream>>>(tokens, emb, pos, X32, XB16);

    // --- QKV projection: [8192,3072], K=1024 (384 blocks, ntn=12) ---
    gemm256<1, 0><<<dim3((MTOK / 256) * ((3 * Dm) / 256)), blk512, 0, stream>>>(
        XB16, WQ16, b_qkv, QKV16, MTOK, 3 * Dm, Dm, 1.f, (3 * Dm) / 256);

    // --- V transpose ---
    transpose_v<<<dim3(Sq / 64, Bz * Hh), blk, 0, stream>>>(QKV16, VT16);

    // --- fused flash attention -> CTX16 ---
    flash_attn<<<dim3(Sq / 128, Bz * Hh), blk, 0, stream>>>(QKV16, VT16, CTX16);

    // --- attn_out = ctx @ w_o^T + b_o (fp32), [8192,1024] K=1024 (ntn=4) ---
    gemm256<0, 0><<<dim3((MTOK / 256) * (Dm / 256)), blk512, 0, stream>>>(
        CTX16, WO16, b_o, ATT32, MTOK, Dm, Dm, 1.f, Dm / 256);

    // --- LN1 ---
    ln_kernel<1><<<MTOK, blk, 0, stream>>>(X32, ATT32, g1, beta1, XB16);

    // --- FFN1: h = relu(x1 @ w1^T + b1), [8192,4096] K=1024 (ntn=16) ---
    gemm256<1, 1><<<dim3((MTOK / 256) * (DFFm / 256)), blk512, 0, stream>>>(
        XB16, W116, b1, H16, MTOK, DFFm, Dm, 1.f, DFFm / 256);

    // --- FFN2: ffn = h @ w2^T + b2 (fp32), [8192,1024] K=4096 (ntn=4) ---
    gemm256<0, 0><<<dim3((MTOK / 256) * (Dm / 256)), blk512, 0, stream>>>(
        H16, W216, b2, ATT32, MTOK, Dm, DFFm, 1.f, Dm / 256);

    // --- LN2 ---
    ln_kernel<0><<<MTOK, blk, 0, stream>>>(X32, ATT32, g2, beta2, XB16);

    // --- final vocab projection: [8192,32000] K=1024 (4000 blocks, ntn=125) ---
    gemm256<0, 0><<<dim3((MTOK / 256) * (Vv / 256)), blk512, 0, stream>>>(
        XB16, WFC16, b_fc, (float*)d_out, MTOK, Vv, Dm, 1.f, Vv / 256);
}